// Round 17
// baseline (292.396 us; speedup 1.0000x reference)
//
#include <hip/hip_runtime.h>
#include <math.h>

constexpr int CN = 256;        // channels
constexpr int NHEAD = 8;       // attention heads
constexpr int KPG = 88;        // nodes per graph
constexpr int NIDF = 16;       // input node features
constexpr int GATE_DIM = 128;
constexpr int ACT_DIM = 4644;
constexpr float LOG2E = 1.4426950408889634f;

typedef __attribute__((ext_vector_type(8))) short bf16x8;
typedef __attribute__((ext_vector_type(4))) float f32x4;

__device__ __forceinline__ unsigned short f2bf(float f) {
    unsigned int u = __float_as_uint(f);
    unsigned int r = (u + 0x7fffu + ((u >> 16) & 1u)) >> 16;
    return (unsigned short)r;
}
__device__ __forceinline__ float bf2f(unsigned short h) {
    return __uint_as_float(((unsigned int)h) << 16);
}

__device__ __forceinline__ void glds16(const void* g, void* l) {
    __builtin_amdgcn_global_load_lds(
        (const __attribute__((address_space(1))) unsigned int*)g,
        (__attribute__((address_space(3))) unsigned int*)l, 16, 0, 0);
}

// raw v_exp_f32: w = 2^x  (inputs pre-scaled by log2e; clamped <= 80, -inf -> 0)
__device__ __forceinline__ float fexp2(float x) {
    float r;
    asm("v_exp_f32 %0, %1" : "=v"(r) : "v"(x));
    return r;
}

// 8-lane group sum via DPP (VALU-speed, no LDS pipe)
__device__ __forceinline__ float grp8_sum(float p) {
    int t;
    t = __builtin_amdgcn_mov_dpp(__float_as_int(p), 0xB1, 0xF, 0xF, true);
    p += __int_as_float(t);
    t = __builtin_amdgcn_mov_dpp(__float_as_int(p), 0x4E, 0xF, 0xF, true);
    p += __int_as_float(t);
    t = __builtin_amdgcn_mov_dpp(__float_as_int(p), 0x141, 0xF, 0xF, true);
    p += __int_as_float(t);
    return p;
}

// ---------------------------------------------------------------------------
// CSR build: count -> scan (2 kernels) -> fill (csrcB = byte offsets)
// ---------------------------------------------------------------------------
__global__ void count_kernel(const int* __restrict__ dst, int* __restrict__ cnt, int E) {
    int e = blockIdx.x * 256 + threadIdx.x;
    if (e < E) atomicAdd(&cnt[dst[e]], 1);
}

__global__ __launch_bounds__(1024) void scan1_kernel(const int* __restrict__ cnt,
                                                     int* __restrict__ rowptr,
                                                     int* __restrict__ btot, int n) {
    __shared__ int buf[1024];
    int tid = threadIdx.x;
    int i = blockIdx.x * 1024 + tid;
    int v = (i < n) ? cnt[i] : 0;
    buf[tid] = v;
    __syncthreads();
    for (int off = 1; off < 1024; off <<= 1) {
        int t = (tid >= off) ? buf[tid - off] : 0;
        __syncthreads();
        buf[tid] += t;
        __syncthreads();
    }
    if (i < n) rowptr[i] = buf[tid] - v;
    if (tid == 1023) btot[blockIdx.x] = buf[1023];
}

// adds prefix of btot inline (nb <= 32, each thread sums serially)
__global__ __launch_bounds__(1024) void scan3_kernel(int* __restrict__ rowptr,
                                                     const int* __restrict__ btot,
                                                     int n, int nb) {
    int i = blockIdx.x * 1024 + threadIdx.x;
    int b = i >> 10;
    if (i < n) {
        int pre = 0;
        for (int k = 0; k < b; ++k) pre += btot[k];
        rowptr[i] += pre;
    } else if (i == n) {
        int pre = 0;
        for (int k = 0; k < nb; ++k) pre += btot[k];
        rowptr[n] = pre;
    }
}

__global__ void fill_kernel(const int* __restrict__ src, const int* __restrict__ dst,
                            const int* __restrict__ rowptr, int* __restrict__ cursor,
                            int* __restrict__ csrcB, int E) {
    int e = blockIdx.x * 256 + threadIdx.x;
    if (e < E) {
        int d = dst[e];
        int p = atomicAdd(&cursor[d], 1);
        csrcB[rowptr[d] + p] = src[e] * 1024;   // byte offset into bf16 xlr (512 bf16/row)
    }
}

// ---------------------------------------------------------------------------
// Embedding: h = relu(x @ W_emb + b_emb) + pos_emb[n % 88]; bf16 hi only
// ---------------------------------------------------------------------------
__global__ __launch_bounds__(256) void embed_kernel(const float* __restrict__ x,
                                                    const float* __restrict__ Wemb,
                                                    const float* __restrict__ bemb,
                                                    const float* __restrict__ pos,
                                                    float* __restrict__ h,
                                                    unsigned short* __restrict__ hh) {
    __shared__ float Wl[NIDF][CN];
    int tid = threadIdx.x;
    for (int i = tid; i < NIDF * CN; i += 256) Wl[i >> 8][i & 255] = Wemb[i];
    __syncthreads();
    float bias = bemb[tid];
    int node0 = blockIdx.x * 16;
    for (int q = 0; q < 16; ++q) {
        int n = node0 + q;
        float acc = bias;
        #pragma unroll
        for (int k = 0; k < NIDF; ++k) acc += x[n * NIDF + k] * Wl[k][tid];
        float val = fmaxf(acc, 0.f) + pos[(n % KPG) * CN + tid];
        h[(size_t)n * CN + tid] = val;
        hh[(size_t)n * CN + tid] = f2bf(val);
    }
}

// ---------------------------------------------------------------------------
// Weight relayout kernels. *_h variants emit bf16 hi only (for PROD=1 GEMMs).
// ---------------------------------------------------------------------------
__global__ void wconv_cat_h_kernel(const float* __restrict__ Ws, const float* __restrict__ Wd,
                                   unsigned short* __restrict__ Bh, int NB, int tot) {
    int o = blockIdx.x * 256 + threadIdx.x;
    if (o >= tot) return;
    int l4 = blockIdx.y;
    const float* ws = Ws + (size_t)l4 * 256 * 256;
    const float* wd = Wd + (size_t)l4 * 256 * 256;
    int idx = o & 511;
    int nb = (o >> 9) % NB;
    int kb = o / (512 * NB);
    int l = idx >> 3, j = idx & 7;
    int k = kb * 32 + (l >> 4) * 8 + j;
    int c = nb * 16 + (l & 15);
    float v = (c < 256) ? ws[(size_t)k * 256 + c] : wd[(size_t)k * 256 + (c - 256)];
    Bh[(size_t)l4 * tot + o] = f2bf(v);
}

__global__ void wconv_h_kernel(const float* __restrict__ W, unsigned short* __restrict__ Bh,
                               int Nn, int NB, int tot) {
    int o = blockIdx.x * 256 + threadIdx.x;
    if (o >= tot) return;
    int idx = o & 511;
    int nb = (o >> 9) % NB;
    int kb = o / (512 * NB);
    int l = idx >> 3, j = idx & 7;
    int k = kb * 32 + (l >> 4) * 8 + j;
    int c = nb * 16 + (l & 15);
    float v = (c < Nn) ? W[(size_t)k * Nn + c] : 0.f;
    Bh[o] = f2bf(v);
}

__global__ void wconv_kernel(const float* __restrict__ W, unsigned short* __restrict__ Bh,
                             unsigned short* __restrict__ Bl, int Nn, int NB, int tot) {
    int o = blockIdx.x * 256 + threadIdx.x;
    if (o >= tot) return;
    int idx = o & 511;
    int nb = (o >> 9) % NB;
    int kb = o / (512 * NB);
    int l = idx >> 3, j = idx & 7;
    int k = kb * 32 + (l >> 4) * 8 + j;
    int c = nb * 16 + (l & 15);
    float v = (c < Nn) ? W[(size_t)k * Nn + c] : 0.f;
    unsigned short hh = f2bf(v);
    Bh[o] = hh;
    Bl[o] = f2bf(v - bf2f(hh));
}

// ---------------------------------------------------------------------------
// MFMA GEMM, bf16 split: C = A @ B (+bias).
// PROD=1: AhBh only. PROD=2: +AhBl. PROD=3: +AlBh.
// OBF16 : emit C as bf16.  NBT: B-tile width in 16-col blocks.
// ---------------------------------------------------------------------------
template <bool BIAS, int PROD, bool OBF16, int NBT>
__global__ __launch_bounds__(256) void mgemm(const unsigned short* __restrict__ Ah,
                                             const unsigned short* __restrict__ Al,
                                             const unsigned short* __restrict__ Bh,
                                             const unsigned short* __restrict__ Bl,
                                             const float* __restrict__ bias,
                                             void* __restrict__ Cv,
                                             int M, int Nlog, int NB, int K) {
    constexpr int NF = NBT / 2;           // per-wave N fragments
    __shared__ unsigned short AhL[8 * 64 * 8];
    __shared__ unsigned short AlL[(PROD >= 3) ? 8 * 64 * 8 : 16];
    __shared__ unsigned short BhL[NBT * 512];
    __shared__ unsigned short BlL[(PROD >= 2) ? NBT * 512 : 16];
    int tid = threadIdx.x;
    int wid = tid >> 6, lane = tid & 63;
    int row0 = blockIdx.x * 128;
    int cb = blockIdx.y;
    int wr = wid >> 1, wc = wid & 1;

    int rr = lane & 15, kq = lane >> 4;

    f32x4 acc[4][NF] = {};

    for (int k0 = 0; k0 < K; k0 += 32) {
        int kb = k0 >> 5;
        {
            int mb0 = wid * 2;
            const unsigned short* s0 = Ah + (size_t)(row0 + mb0 * 16 + rr) * K + k0 + kq * 8;
            const unsigned short* s1 = Ah + (size_t)(row0 + mb0 * 16 + 16 + rr) * K + k0 + kq * 8;
            glds16(s0, &AhL[mb0 * 512]);
            glds16(s1, &AhL[mb0 * 512 + 512]);
            if constexpr (PROD >= 3) {
                const unsigned short* t0 = Al + (size_t)(row0 + mb0 * 16 + rr) * K + k0 + kq * 8;
                const unsigned short* t1 = Al + (size_t)(row0 + mb0 * 16 + 16 + rr) * K + k0 + kq * 8;
                glds16(t0, &AlL[mb0 * 512]);
                glds16(t1, &AlL[mb0 * 512 + 512]);
            }
        }
        {
            size_t base = ((size_t)kb * NB + (size_t)cb * NBT) * 512;
            for (int ch = wid; ch < NBT; ch += 4) {
                glds16(Bh + base + ch * 512 + lane * 8, &BhL[ch * 512]);
                if constexpr (PROD >= 2)
                    glds16(Bl + base + ch * 512 + lane * 8, &BlL[ch * 512]);
            }
        }
        __syncthreads();
        bf16x8 a_h[4], a_l[4], b_h[NF], b_l[NF];
        #pragma unroll
        for (int mf = 0; mf < 4; ++mf) {
            int off = ((wr * 4 + mf) * 64 + lane) * 8;
            a_h[mf] = *reinterpret_cast<const bf16x8*>(&AhL[off]);
            if constexpr (PROD >= 3)
                a_l[mf] = *reinterpret_cast<const bf16x8*>(&AlL[off]);
        }
        #pragma unroll
        for (int nf = 0; nf < NF; ++nf) {
            int off = ((wc * NF + nf) * 64 + lane) * 8;
            b_h[nf] = *reinterpret_cast<const bf16x8*>(&BhL[off]);
            if constexpr (PROD >= 2)
                b_l[nf] = *reinterpret_cast<const bf16x8*>(&BlL[off]);
        }
        #pragma unroll
        for (int mf = 0; mf < 4; ++mf)
            #pragma unroll
            for (int nf = 0; nf < NF; ++nf) {
                acc[mf][nf] = __builtin_amdgcn_mfma_f32_16x16x32_bf16(a_h[mf], b_h[nf], acc[mf][nf], 0, 0, 0);
                if constexpr (PROD >= 2)
                    acc[mf][nf] = __builtin_amdgcn_mfma_f32_16x16x32_bf16(a_h[mf], b_l[nf], acc[mf][nf], 0, 0, 0);
                if constexpr (PROD >= 3)
                    acc[mf][nf] = __builtin_amdgcn_mfma_f32_16x16x32_bf16(a_l[mf], b_h[nf], acc[mf][nf], 0, 0, 0);
            }
        __syncthreads();
    }
    #pragma unroll
    for (int mf = 0; mf < 4; ++mf) {
        #pragma unroll
        for (int nf = 0; nf < NF; ++nf) {
            int col = cb * (NBT * 16) + wc * (NF * 16) + nf * 16 + (lane & 15);
            if (col < Nlog) {
                float bv = BIAS ? bias[col] : 0.f;
                #pragma unroll
                for (int rg = 0; rg < 4; ++rg) {
                    int row = row0 + wr * 64 + mf * 16 + (lane >> 4) * 4 + rg;
                    float r = acc[mf][nf][rg] + bv;
                    if constexpr (OBF16)
                        ((unsigned short*)Cv)[(size_t)row * Nlog + col] = f2bf(r);
                    else
                        ((float*)Cv)[(size_t)row * Nlog + col] = r;
                }
            }
        }
    }
}

// ---------------------------------------------------------------------------
// GAT aggregate v14: one wave per block, two consecutive nodes per wave;
// loads for BOTH streams issued before both computes (2-group load distance).
// bf16 xlr gather, scalarized CSR walk, base-2 no-max softmax, DPP reduce,
// XCD swizzle.
// ---------------------------------------------------------------------------
__global__ __launch_bounds__(64) void gat_agg(const unsigned short* __restrict__ xlr,
                                              const int* __restrict__ rowptr,
                                              const int* __restrict__ csrcB,
                                              const float* __restrict__ att,
                                              const float* __restrict__ bias,
                                              const float* __restrict__ lng,
                                              const float* __restrict__ lnb,
                                              float* __restrict__ h,
                                              unsigned short* __restrict__ hh) {
    int cpx = gridDim.x >> 3;
    int swz = (blockIdx.x & 7) * cpx + (blockIdx.x >> 3);
    int lane = threadIdx.x;
    int na = __builtin_amdgcn_readfirstlane(swz * 2);
    int nb_ = na + 1;
    int voff = lane * 8;                      // byte offset (4 bf16/lane)

    ushort4 ua = *reinterpret_cast<const ushort4*>(xlr + (size_t)na * 512 + 256 + lane * 4);
    ushort4 ub = *reinterpret_cast<const ushort4*>(xlr + (size_t)nb_ * 512 + 256 + lane * 4);
    float xa0 = bf2f(ua.x), xa1 = bf2f(ua.y), xa2 = bf2f(ua.z), xa3 = bf2f(ua.w);
    float xb0 = bf2f(ub.x), xb1 = bf2f(ub.y), xb2 = bf2f(ub.z), xb3 = bf2f(ub.w);
    float4 at4 = *reinterpret_cast<const float4*>(att + lane * 4);
    at4.x *= LOG2E; at4.y *= LOG2E; at4.z *= LOG2E; at4.w *= LOG2E;

    int e0a = __builtin_amdgcn_readfirstlane(rowptr[na]);
    int e1a = __builtin_amdgcn_readfirstlane(rowptr[na + 1]);
    int e1b = __builtin_amdgcn_readfirstlane(rowptr[nb_ + 1]);
    int e0b = e1a;   // consecutive nodes, contiguous CSR

    float sA = 0.f, aA0 = 0.f, aA1 = 0.f, aA2 = 0.f, aA3 = 0.f;
    float sB = 0.f, aB0 = 0.f, aB1 = 0.f, aB2 = 0.f, aB3 = 0.f;
    const char* xB = (const char*)xlr;

    auto ld4 = [&](ushort4* X, int eb, int last) {
        if (eb + 3 <= last) {
            #pragma unroll
            for (int j = 0; j < 4; ++j) {
                int f = csrcB[eb + j];
                X[j] = *reinterpret_cast<const ushort4*>(xB + (unsigned)f + voff);
            }
        } else {
            #pragma unroll
            for (int j = 0; j < 4; ++j) {
                int f = csrcB[min(eb + j, last)];
                X[j] = *reinterpret_cast<const ushort4*>(xB + (unsigned)f + voff);
            }
        }
    };
    auto group4 = [&](const ushort4* X, int eb, int e1,
                      float xr0, float xr1, float xr2, float xr3,
                      float& s_r, float& a0, float& a1, float& a2, float& a3) {
        float xf[4][4];
        #pragma unroll
        for (int j = 0; j < 4; ++j) {
            xf[j][0] = bf2f(X[j].x);
            xf[j][1] = bf2f(X[j].y);
            xf[j][2] = bf2f(X[j].z);
            xf[j][3] = bf2f(X[j].w);
        }
        float p[4];
        #pragma unroll
        for (int j = 0; j < 4; ++j) {
            float z, pp = 0.f;
            z = xf[j][0] + xr0; z = fmaxf(z, 0.2f * z); pp += z * at4.x;
            z = xf[j][1] + xr1; z = fmaxf(z, 0.2f * z); pp += z * at4.y;
            z = xf[j][2] + xr2; z = fmaxf(z, 0.2f * z); pp += z * at4.z;
            z = xf[j][3] + xr3; z = fmaxf(z, 0.2f * z); pp += z * at4.w;
            p[j] = grp8_sum(pp);
        }
        float w[4];
        if (eb + 3 < e1) {
            #pragma unroll
            for (int j = 0; j < 4; ++j) w[j] = fexp2(fminf(p[j], 80.f));
        } else {
            #pragma unroll
            for (int j = 0; j < 4; ++j) {
                float pc = (eb + j < e1) ? fminf(p[j], 80.f) : -INFINITY;
                w[j] = fexp2(pc);
            }
        }
        s_r += (w[0] + w[1]) + (w[2] + w[3]);
        #pragma unroll
        for (int j = 0; j < 4; ++j) {
            a0 += w[j] * xf[j][0];
            a1 += w[j] * xf[j][1];
            a2 += w[j] * xf[j][2];
            a3 += w[j] * xf[j][3];
        }
    };

    ushort4 A[4], B[4], TA[4], TB[4];
    int eA = e0a, eB = e0b;
    ld4(A, eA, e1a - 1);
    ld4(B, eB, e1b - 1);
    // joint loop: issue both next-loads before both computes (2-group distance)
    while (eA < e1a && eB < e1b) {
        #pragma unroll
        for (int j = 0; j < 4; ++j) { TA[j] = A[j]; TB[j] = B[j]; }
        if (eA + 4 < e1a) ld4(A, eA + 4, e1a - 1);
        if (eB + 4 < e1b) ld4(B, eB + 4, e1b - 1);
        group4(TA, eA, e1a, xa0, xa1, xa2, xa3, sA, aA0, aA1, aA2, aA3);
        group4(TB, eB, e1b, xb0, xb1, xb2, xb3, sB, aB0, aB1, aB2, aB3);
        eA += 4;
        eB += 4;
    }
    while (eA < e1a) {
        #pragma unroll
        for (int j = 0; j < 4; ++j) TA[j] = A[j];
        if (eA + 4 < e1a) ld4(A, eA + 4, e1a - 1);
        group4(TA, eA, e1a, xa0, xa1, xa2, xa3, sA, aA0, aA1, aA2, aA3);
        eA += 4;
    }
    while (eB < e1b) {
        #pragma unroll
        for (int j = 0; j < 4; ++j) TB[j] = B[j];
        if (eB + 4 < e1b) ld4(B, eB + 4, e1b - 1);
        group4(TB, eB, e1b, xb0, xb1, xb2, xb3, sB, aB0, aB1, aB2, aB3);
        eB += 4;
    }

    auto finish = [&](int n, float s_r, float a0, float a1, float a2, float a3) {
        float inv = 1.f / s_r;
        float4 hr4 = *reinterpret_cast<const float4*>(h + (size_t)n * CN + lane * 4);
        float4 bi4 = *reinterpret_cast<const float4*>(bias + lane * 4);
        float v0 = hr4.x + fmaxf(a0 * inv + bi4.x, 0.f);
        float v1 = hr4.y + fmaxf(a1 * inv + bi4.y, 0.f);
        float v2 = hr4.z + fmaxf(a2 * inv + bi4.z, 0.f);
        float v3 = hr4.w + fmaxf(a3 * inv + bi4.w, 0.f);
        float sum = v0 + v1 + v2 + v3;
        float sq = v0 * v0 + v1 * v1 + v2 * v2 + v3 * v3;
        #pragma unroll
        for (int o = 32; o; o >>= 1) { sum += __shfl_xor(sum, o); sq += __shfl_xor(sq, o); }
        float mu = sum / CN;
        float var = sq / CN - mu * mu;
        float ninv = rsqrtf(var + 1e-5f);
        float4 lg4 = *reinterpret_cast<const float4*>(lng + lane * 4);
        float4 lb4 = *reinterpret_cast<const float4*>(lnb + lane * 4);
        float o0 = (v0 - mu) * ninv * lg4.x + lb4.x;
        float o1 = (v1 - mu) * ninv * lg4.y + lb4.y;
        float o2 = (v2 - mu) * ninv * lg4.z + lb4.z;
        float o3 = (v3 - mu) * ninv * lg4.w + lb4.w;
        *reinterpret_cast<float4*>(h + (size_t)n * CN + lane * 4) = make_float4(o0, o1, o2, o3);
        ushort4 uh;
        uh.x = f2bf(o0); uh.y = f2bf(o1); uh.z = f2bf(o2); uh.w = f2bf(o3);
        *reinterpret_cast<ushort4*>(hh + (size_t)n * CN + lane * 4) = uh;
    };
    finish(na, sA, aA0, aA1, aA2, aA3);
    finish(nb_, sB, aB0, aB1, aB2, aB3);
}

// ---------------------------------------------------------------------------
// gate[n] = relu(gtmp[n]) . gW2 + gb2
// ---------------------------------------------------------------------------
__global__ __launch_bounds__(256) void gate2_kernel(const float* __restrict__ gtmp,
                                                    const float* __restrict__ gW2,
                                                    const float* __restrict__ gb2,
                                                    float* __restrict__ gate, int N) {
    int n = blockIdx.x * 4 + (threadIdx.x >> 6);
    if (n >= N) return;
    int lane = threadIdx.x & 63;
    float2 t = *reinterpret_cast<const float2*>(gtmp + (size_t)n * GATE_DIM + lane * 2);
    float2 w = *reinterpret_cast<const float2*>(gW2 + lane * 2);
    float c = fmaxf(t.x, 0.f) * w.x + fmaxf(t.y, 0.f) * w.y;
    #pragma unroll
    for (int o = 32; o; o >>= 1) c += __shfl_xor(c, o);
    if (lane == 0) gate[n] = c + gb2[0];
}

// ---------------------------------------------------------------------------
// Pool: segment softmax over contiguous 88-node graphs + weighted sum -> emb
// ---------------------------------------------------------------------------
__global__ __launch_bounds__(256) void pool_kernel(const float* __restrict__ gate,
                                                   const float* __restrict__ h,
                                                   float* __restrict__ emb) {
    __shared__ float a[KPG];
    __shared__ float wm[4];
    int g = blockIdx.x, tid = threadIdx.x;
    int wid = tid >> 6, lane = tid & 63;
    float gv = (tid < KPG) ? gate[g * KPG + tid] : -INFINITY;
    float m = gv;
    #pragma unroll
    for (int o = 32; o; o >>= 1) m = fmaxf(m, __shfl_xor(m, o));
    if (lane == 0) wm[wid] = m;
    __syncthreads();
    m = fmaxf(fmaxf(wm[0], wm[1]), fmaxf(wm[2], wm[3]));
    __syncthreads();
    float av = (tid < KPG) ? expf(gv - m) : 0.f;
    if (tid < KPG) a[tid] = av;
    float s = av;
    #pragma unroll
    for (int o = 32; o; o >>= 1) s += __shfl_xor(s, o);
    if (lane == 0) wm[wid] = s;
    __syncthreads();
    s = wm[0] + wm[1] + wm[2] + wm[3];
    float inv = 1.f / s;
    float acc = 0.f;
    const float* hg = h + (size_t)g * KPG * CN;
    for (int i = 0; i < KPG; ++i) acc += a[i] * hg[i * CN + tid];
    emb[(size_t)g * CN + tid] = acc * inv;
}

// ---------------------------------------------------------------------------
// Heads: t1 = relu(LN(emb@pW1+pb1)) (bf16 hi/lo out); value head full
// ---------------------------------------------------------------------------
__global__ __launch_bounds__(256) void head_kernel(const float* __restrict__ emb,
    const float* __restrict__ pW1, const float* __restrict__ pb1,
    const float* __restrict__ plng, const float* __restrict__ plnb,
    const float* __restrict__ vW1, const float* __restrict__ vb1,
    const float* __restrict__ vW2, const float* __restrict__ vb2,
    unsigned short* __restrict__ t1h, unsigned short* __restrict__ t1l,
    float* __restrict__ value_out) {
    __shared__ float e_l[CN];
    __shared__ float rsum[4], rsq[4];
    int g = blockIdx.x, tid = threadIdx.x;
    int wid = tid >> 6, lane = tid & 63;
    e_l[tid] = emb[(size_t)g * CN + tid];
    __syncthreads();
    float p = pb1[tid], v = vb1[tid];
    for (int k = 0; k < CN; ++k) {
        float e = e_l[k];
        p += e * pW1[k * CN + tid];
        v += e * vW1[k * CN + tid];
    }
    float sum = p, sq = p * p;
    #pragma unroll
    for (int o = 32; o; o >>= 1) { sum += __shfl_xor(sum, o); sq += __shfl_xor(sq, o); }
    if (lane == 0) { rsum[wid] = sum; rsq[wid] = sq; }
    __syncthreads();
    sum = rsum[0] + rsum[1] + rsum[2] + rsum[3];
    sq  = rsq[0] + rsq[1] + rsq[2] + rsq[3];
    float mu = sum / CN;
    float var = sq / CN - mu * mu;
    float inv = rsqrtf(var + 1e-5f);
    float t1v = fmaxf((p - mu) * inv * plng[tid] + plnb[tid], 0.f);
    unsigned short th = f2bf(t1v);
    t1h[(size_t)g * CN + tid] = th;
    t1l[(size_t)g * CN + tid] = f2bf(t1v - bf2f(th));
    float contrib = fmaxf(v, 0.f) * vW2[tid];
    __syncthreads();
    #pragma unroll
    for (int o = 32; o; o >>= 1) contrib += __shfl_xor(contrib, o);
    if (lane == 0) rsum[wid] = contrib;
    __syncthreads();
    if (tid == 0)
        value_out[g] = tanhf(rsum[0] + rsum[1] + rsum[2] + rsum[3] + vb2[0]);
}

// ---------------------------------------------------------------------------
extern "C" void kernel_launch(void* const* d_in, const int* in_sizes, int n_in,
                              void* d_out, int out_size, void* d_ws, size_t ws_size,
                              hipStream_t stream) {
    const float* x        = (const float*)d_in[0];
    const int*   ei       = (const int*)d_in[1];
    const float* W_emb    = (const float*)d_in[4];
    const float* b_emb    = (const float*)d_in[5];
    const float* pos_emb  = (const float*)d_in[6];
    const float* gat_Wsrc = (const float*)d_in[7];
    const float* gat_Wdst = (const float*)d_in[8];
    const float* gat_att  = (const float*)d_in[9];
    const float* gat_bias = (const float*)d_in[10];
    const float* ln_g     = (const float*)d_in[11];
    const float* ln_b     = (const float*)d_in[12];
    const float* gW1      = (const float*)d_in[13];
    const float* gb1      = (const float*)d_in[14];
    const float* gW2      = (const float*)d_in[15];
    const float* gb2      = (const float*)d_in[16];
    const float* pW1      = (const float*)d_in[17];
    const float* pb1      = (const float*)d_in[18];
    const float* p_ln_g   = (const float*)d_in[19];
    const float* p_ln_b   = (const float*)d_in[20];
    const float* pW2      = (const float*)d_in[21];
    const float* pb2      = (const float*)d_in[22];
    const float* vW1      = (const float*)d_in[23];
    const float* vb1      = (const float*)d_in[24];
    const float* vW2      = (const float*)d_in[25];
    const float* vb2      = (const float*)d_in[26];

    const int N = in_sizes[2];      // 22528
    const int E = in_sizes[1] / 2;  // 405504
    const int G = N / KPG;          // 256
    const int NB_SC = (N + 1023) / 1024;

    const int NB_CAT = 32;                        // 512/16
    const int NB_G1  = 8;                         // 128/16
    const int GY_POL = (ACT_DIM + 63) / 64;       // 73 (BN=64 tiles)
    const int NB_POL = GY_POL * 4;                // 292

    char* ws = (char*)d_ws;
    size_t off = 0;
    auto alloc = [&](size_t nbytes) {
        void* pp = ws + off;
        off = (off + nbytes + 255) & ~(size_t)255;
        return pp;
    };
    float* h      = (float*)alloc((size_t)N * CN * 4);
    unsigned short* hh = (unsigned short*)alloc((size_t)N * CN * 2);
    unsigned short* xlr = (unsigned short*)alloc((size_t)N * 512 * 2);   // bf16
    float* gtmp   = (float*)alloc((size_t)N * GATE_DIM * 4);
    unsigned short* WcatH = (unsigned short*)alloc((size_t)4 * 8 * NB_CAT * 512 * 2);
    unsigned short* gW1H  = (unsigned short*)alloc((size_t)8 * NB_G1 * 512 * 2);
    unsigned short* pW2H  = (unsigned short*)alloc((size_t)8 * NB_POL * 512 * 2);
    unsigned short* pW2L  = (unsigned short*)alloc((size_t)8 * NB_POL * 512 * 2);
    float* gate   = (float*)alloc((size_t)N * 4);
    float* emb    = (float*)alloc((size_t)G * CN * 4);
    unsigned short* t1h = (unsigned short*)alloc((size_t)G * CN * 2);
    unsigned short* t1l = (unsigned short*)alloc((size_t)G * CN * 2);
    int*   rowptr = (int*)alloc((size_t)(N + 1) * 4);
    int*   cnt    = (int*)alloc((size_t)N * 4);
    int*   cursor = (int*)alloc((size_t)N * 4);
    int*   btot   = (int*)alloc((size_t)64 * 4);
    int*   csrcB  = (int*)alloc((size_t)E * 4);

    const int* e_src = ei;
    const int* e_dst = ei + E;

    hipMemsetAsync(cnt, 0, (size_t)N * 4, stream);
    hipMemsetAsync(cursor, 0, (size_t)N * 4, stream);
    count_kernel<<<(E + 255) / 256, 256, 0, stream>>>(e_dst, cnt, E);
    scan1_kernel<<<NB_SC, 1024, 0, stream>>>(cnt, rowptr, btot, N);
    scan3_kernel<<<(N + 1024) / 1024, 1024, 0, stream>>>(rowptr, btot, N, NB_SC);
    fill_kernel<<<(E + 255) / 256, 256, 0, stream>>>(e_src, e_dst, rowptr, cursor, csrcB, E);

    embed_kernel<<<N / 16, 256, 0, stream>>>(x, W_emb, b_emb, pos_emb, h, hh);

    {
        int totc = 8 * NB_CAT * 512;
        dim3 gw((totc + 255) / 256, 4);
        wconv_cat_h_kernel<<<gw, 256, 0, stream>>>(gat_Wsrc, gat_Wdst, WcatH, NB_CAT, totc);
        int totg = 8 * NB_G1 * 512;
        wconv_h_kernel<<<(totg + 255) / 256, 256, 0, stream>>>(gW1, gW1H, GATE_DIM, NB_G1, totg);
        int totp = 8 * NB_POL * 512;
        wconv_kernel<<<(totp + 255) / 256, 256, 0, stream>>>(pW2, pW2H, pW2L, ACT_DIM, NB_POL, totp);
    }

    for (int l = 0; l < 4; ++l) {
        size_t wo = (size_t)l * 8 * NB_CAT * 512;
        dim3 g1(N / 128, 512 / 128);
        mgemm<false, 1, true, 8><<<g1, 256, 0, stream>>>(hh, nullptr, WcatH + wo, nullptr,
                                                         nullptr, xlr, N, 512, NB_CAT, CN);
        gat_agg<<<N / 2, 64, 0, stream>>>(xlr, rowptr, csrcB, gat_att + l * CN,
                                          gat_bias + l * CN, ln_g + l * CN, ln_b + l * CN,
                                          h, hh);
    }

    // gate MLP
    {
        dim3 g1(N / 128, 1);
        mgemm<true, 1, false, 8><<<g1, 256, 0, stream>>>(hh, nullptr, gW1H, nullptr, gb1,
                                                         gtmp, N, GATE_DIM, NB_G1, CN);
        gate2_kernel<<<(N + 3) / 4, 256, 0, stream>>>(gtmp, gW2, gb2, gate, N);
    }
    pool_kernel<<<G, 256, 0, stream>>>(gate, h, emb);

    float* policy = (float*)d_out;
    float* value  = (float*)d_out + (size_t)G * ACT_DIM;
    head_kernel<<<G, 256, 0, stream>>>(emb, pW1, pb1, p_ln_g, p_ln_b,
                                       vW1, vb1, vW2, vb2, t1h, t1l, value);
    dim3 g2(G / 128, GY_POL);
    mgemm<true, 3, false, 4><<<g2, 256, 0, stream>>>(t1h, t1l, pW2H, pW2L, pb2,
                                                     policy, G, ACT_DIM, NB_POL, CN);
}

// Round 18
// 284.511 us; speedup vs baseline: 1.0277x; 1.0277x over previous
//
#include <hip/hip_runtime.h>
#include <math.h>

constexpr int CN = 256;        // channels
constexpr int NHEAD = 8;       // attention heads
constexpr int KPG = 88;        // nodes per graph
constexpr int NIDF = 16;       // input node features
constexpr int GATE_DIM = 128;
constexpr int ACT_DIM = 4644;
constexpr float LOG2E = 1.4426950408889634f;

typedef __attribute__((ext_vector_type(8))) short bf16x8;
typedef __attribute__((ext_vector_type(4))) float f32x4;

__device__ __forceinline__ unsigned short f2bf(float f) {
    unsigned int u = __float_as_uint(f);
    unsigned int r = (u + 0x7fffu + ((u >> 16) & 1u)) >> 16;
    return (unsigned short)r;
}
__device__ __forceinline__ float bf2f(unsigned short h) {
    return __uint_as_float(((unsigned int)h) << 16);
}

__device__ __forceinline__ void glds16(const void* g, void* l) {
    __builtin_amdgcn_global_load_lds(
        (const __attribute__((address_space(1))) unsigned int*)g,
        (__attribute__((address_space(3))) unsigned int*)l, 16, 0, 0);
}

// raw v_exp_f32: w = 2^x  (inputs pre-scaled by log2e; clamped <= 80, -inf -> 0)
__device__ __forceinline__ float fexp2(float x) {
    float r;
    asm("v_exp_f32 %0, %1" : "=v"(r) : "v"(x));
    return r;
}

// 8-lane group sum via DPP (VALU-speed, no LDS pipe)
__device__ __forceinline__ float grp8_sum(float p) {
    int t;
    t = __builtin_amdgcn_mov_dpp(__float_as_int(p), 0xB1, 0xF, 0xF, true);
    p += __int_as_float(t);
    t = __builtin_amdgcn_mov_dpp(__float_as_int(p), 0x4E, 0xF, 0xF, true);
    p += __int_as_float(t);
    t = __builtin_amdgcn_mov_dpp(__float_as_int(p), 0x141, 0xF, 0xF, true);
    p += __int_as_float(t);
    return p;
}

// ---------------------------------------------------------------------------
// CSR build: count -> scan (2 kernels) -> fill (csrcB = byte offsets)
// ---------------------------------------------------------------------------
__global__ void count_kernel(const int* __restrict__ dst, int* __restrict__ cnt, int E) {
    int e = blockIdx.x * 256 + threadIdx.x;
    if (e < E) atomicAdd(&cnt[dst[e]], 1);
}

__global__ __launch_bounds__(1024) void scan1_kernel(const int* __restrict__ cnt,
                                                     int* __restrict__ rowptr,
                                                     int* __restrict__ btot, int n) {
    __shared__ int buf[1024];
    int tid = threadIdx.x;
    int i = blockIdx.x * 1024 + tid;
    int v = (i < n) ? cnt[i] : 0;
    buf[tid] = v;
    __syncthreads();
    for (int off = 1; off < 1024; off <<= 1) {
        int t = (tid >= off) ? buf[tid - off] : 0;
        __syncthreads();
        buf[tid] += t;
        __syncthreads();
    }
    if (i < n) rowptr[i] = buf[tid] - v;
    if (tid == 1023) btot[blockIdx.x] = buf[1023];
}

// adds prefix of btot inline (nb <= 32, each thread sums serially)
__global__ __launch_bounds__(1024) void scan3_kernel(int* __restrict__ rowptr,
                                                     const int* __restrict__ btot,
                                                     int n, int nb) {
    int i = blockIdx.x * 1024 + threadIdx.x;
    int b = i >> 10;
    if (i < n) {
        int pre = 0;
        for (int k = 0; k < b; ++k) pre += btot[k];
        rowptr[i] += pre;
    } else if (i == n) {
        int pre = 0;
        for (int k = 0; k < nb; ++k) pre += btot[k];
        rowptr[n] = pre;
    }
}

__global__ void fill_kernel(const int* __restrict__ src, const int* __restrict__ dst,
                            const int* __restrict__ rowptr, int* __restrict__ cursor,
                            int* __restrict__ csrcB, int E) {
    int e = blockIdx.x * 256 + threadIdx.x;
    if (e < E) {
        int d = dst[e];
        int p = atomicAdd(&cursor[d], 1);
        csrcB[rowptr[d] + p] = src[e] * 1024;   // byte offset into bf16 xlr (512 bf16/row)
    }
}

// ---------------------------------------------------------------------------
// Embedding: h = relu(x @ W_emb + b_emb) + pos_emb[n % 88]; bf16 hi only
// ---------------------------------------------------------------------------
__global__ __launch_bounds__(256) void embed_kernel(const float* __restrict__ x,
                                                    const float* __restrict__ Wemb,
                                                    const float* __restrict__ bemb,
                                                    const float* __restrict__ pos,
                                                    float* __restrict__ h,
                                                    unsigned short* __restrict__ hh) {
    __shared__ float Wl[NIDF][CN];
    int tid = threadIdx.x;
    for (int i = tid; i < NIDF * CN; i += 256) Wl[i >> 8][i & 255] = Wemb[i];
    __syncthreads();
    float bias = bemb[tid];
    int node0 = blockIdx.x * 16;
    for (int q = 0; q < 16; ++q) {
        int n = node0 + q;
        float acc = bias;
        #pragma unroll
        for (int k = 0; k < NIDF; ++k) acc += x[n * NIDF + k] * Wl[k][tid];
        float val = fmaxf(acc, 0.f) + pos[(n % KPG) * CN + tid];
        h[(size_t)n * CN + tid] = val;
        hh[(size_t)n * CN + tid] = f2bf(val);
    }
}

// ---------------------------------------------------------------------------
// Weight relayout kernels. *_h variants emit bf16 hi only (for PROD=1 GEMMs).
// ---------------------------------------------------------------------------
__global__ void wconv_cat_h_kernel(const float* __restrict__ Ws, const float* __restrict__ Wd,
                                   unsigned short* __restrict__ Bh, int NB, int tot) {
    int o = blockIdx.x * 256 + threadIdx.x;
    if (o >= tot) return;
    int l4 = blockIdx.y;
    const float* ws = Ws + (size_t)l4 * 256 * 256;
    const float* wd = Wd + (size_t)l4 * 256 * 256;
    int idx = o & 511;
    int nb = (o >> 9) % NB;
    int kb = o / (512 * NB);
    int l = idx >> 3, j = idx & 7;
    int k = kb * 32 + (l >> 4) * 8 + j;
    int c = nb * 16 + (l & 15);
    float v = (c < 256) ? ws[(size_t)k * 256 + c] : wd[(size_t)k * 256 + (c - 256)];
    Bh[(size_t)l4 * tot + o] = f2bf(v);
}

__global__ void wconv_h_kernel(const float* __restrict__ W, unsigned short* __restrict__ Bh,
                               int Nn, int NB, int tot) {
    int o = blockIdx.x * 256 + threadIdx.x;
    if (o >= tot) return;
    int idx = o & 511;
    int nb = (o >> 9) % NB;
    int kb = o / (512 * NB);
    int l = idx >> 3, j = idx & 7;
    int k = kb * 32 + (l >> 4) * 8 + j;
    int c = nb * 16 + (l & 15);
    float v = (c < Nn) ? W[(size_t)k * Nn + c] : 0.f;
    Bh[o] = f2bf(v);
}

__global__ void wconv_kernel(const float* __restrict__ W, unsigned short* __restrict__ Bh,
                             unsigned short* __restrict__ Bl, int Nn, int NB, int tot) {
    int o = blockIdx.x * 256 + threadIdx.x;
    if (o >= tot) return;
    int idx = o & 511;
    int nb = (o >> 9) % NB;
    int kb = o / (512 * NB);
    int l = idx >> 3, j = idx & 7;
    int k = kb * 32 + (l >> 4) * 8 + j;
    int c = nb * 16 + (l & 15);
    float v = (c < Nn) ? W[(size_t)k * Nn + c] : 0.f;
    unsigned short hh = f2bf(v);
    Bh[o] = hh;
    Bl[o] = f2bf(v - bf2f(hh));
}

// ---------------------------------------------------------------------------
// MFMA GEMM, bf16 split: C = A @ B (+bias).
// PROD=1: AhBh only. PROD=2: +AhBl. PROD=3: +AlBh.
// OBF16 : emit C as bf16.  NBT: B-tile width in 16-col blocks.
// XSWZ  : 1D grid, XCD-aligned decomposition — block b -> xcd=b&7,
//         bx = xcd*RPX + (b>>3)%RPX, by = (b>>3)/RPX. Aligns row-block bx
//         with the XCD that owns rows 128*bx in gat_agg's node partition.
// ---------------------------------------------------------------------------
template <bool BIAS, int PROD, bool OBF16, int NBT, bool XSWZ>
__global__ __launch_bounds__(256) void mgemm(const unsigned short* __restrict__ Ah,
                                             const unsigned short* __restrict__ Al,
                                             const unsigned short* __restrict__ Bh,
                                             const unsigned short* __restrict__ Bl,
                                             const float* __restrict__ bias,
                                             void* __restrict__ Cv,
                                             int M, int Nlog, int NB, int K, int RPX) {
    constexpr int NF = NBT / 2;           // per-wave N fragments
    __shared__ unsigned short AhL[8 * 64 * 8];
    __shared__ unsigned short AlL[(PROD >= 3) ? 8 * 64 * 8 : 16];
    __shared__ unsigned short BhL[NBT * 512];
    __shared__ unsigned short BlL[(PROD >= 2) ? NBT * 512 : 16];
    int tid = threadIdx.x;
    int wid = tid >> 6, lane = tid & 63;
    int bx, cb;
    if constexpr (XSWZ) {
        int b = blockIdx.x;
        int xcd = b & 7;
        int i = b >> 3;
        bx = xcd * RPX + i % RPX;
        cb = i / RPX;
    } else {
        bx = blockIdx.x;
        cb = blockIdx.y;
    }
    int row0 = bx * 128;
    int wr = wid >> 1, wc = wid & 1;

    int rr = lane & 15, kq = lane >> 4;

    f32x4 acc[4][NF] = {};

    for (int k0 = 0; k0 < K; k0 += 32) {
        int kb = k0 >> 5;
        {
            int mb0 = wid * 2;
            const unsigned short* s0 = Ah + (size_t)(row0 + mb0 * 16 + rr) * K + k0 + kq * 8;
            const unsigned short* s1 = Ah + (size_t)(row0 + mb0 * 16 + 16 + rr) * K + k0 + kq * 8;
            glds16(s0, &AhL[mb0 * 512]);
            glds16(s1, &AhL[mb0 * 512 + 512]);
            if constexpr (PROD >= 3) {
                const unsigned short* t0 = Al + (size_t)(row0 + mb0 * 16 + rr) * K + k0 + kq * 8;
                const unsigned short* t1 = Al + (size_t)(row0 + mb0 * 16 + 16 + rr) * K + k0 + kq * 8;
                glds16(t0, &AlL[mb0 * 512]);
                glds16(t1, &AlL[mb0 * 512 + 512]);
            }
        }
        {
            size_t base = ((size_t)kb * NB + (size_t)cb * NBT) * 512;
            for (int ch = wid; ch < NBT; ch += 4) {
                glds16(Bh + base + ch * 512 + lane * 8, &BhL[ch * 512]);
                if constexpr (PROD >= 2)
                    glds16(Bl + base + ch * 512 + lane * 8, &BlL[ch * 512]);
            }
        }
        __syncthreads();
        bf16x8 a_h[4], a_l[4], b_h[NF], b_l[NF];
        #pragma unroll
        for (int mf = 0; mf < 4; ++mf) {
            int off = ((wr * 4 + mf) * 64 + lane) * 8;
            a_h[mf] = *reinterpret_cast<const bf16x8*>(&AhL[off]);
            if constexpr (PROD >= 3)
                a_l[mf] = *reinterpret_cast<const bf16x8*>(&AlL[off]);
        }
        #pragma unroll
        for (int nf = 0; nf < NF; ++nf) {
            int off = ((wc * NF + nf) * 64 + lane) * 8;
            b_h[nf] = *reinterpret_cast<const bf16x8*>(&BhL[off]);
            if constexpr (PROD >= 2)
                b_l[nf] = *reinterpret_cast<const bf16x8*>(&BlL[off]);
        }
        #pragma unroll
        for (int mf = 0; mf < 4; ++mf)
            #pragma unroll
            for (int nf = 0; nf < NF; ++nf) {
                acc[mf][nf] = __builtin_amdgcn_mfma_f32_16x16x32_bf16(a_h[mf], b_h[nf], acc[mf][nf], 0, 0, 0);
                if constexpr (PROD >= 2)
                    acc[mf][nf] = __builtin_amdgcn_mfma_f32_16x16x32_bf16(a_h[mf], b_l[nf], acc[mf][nf], 0, 0, 0);
                if constexpr (PROD >= 3)
                    acc[mf][nf] = __builtin_amdgcn_mfma_f32_16x16x32_bf16(a_l[mf], b_h[nf], acc[mf][nf], 0, 0, 0);
            }
        __syncthreads();
    }
    #pragma unroll
    for (int mf = 0; mf < 4; ++mf) {
        #pragma unroll
        for (int nf = 0; nf < NF; ++nf) {
            int col = cb * (NBT * 16) + wc * (NF * 16) + nf * 16 + (lane & 15);
            if (col < Nlog) {
                float bv = BIAS ? bias[col] : 0.f;
                #pragma unroll
                for (int rg = 0; rg < 4; ++rg) {
                    int row = row0 + wr * 64 + mf * 16 + (lane >> 4) * 4 + rg;
                    float r = acc[mf][nf][rg] + bv;
                    if constexpr (OBF16)
                        ((unsigned short*)Cv)[(size_t)row * Nlog + col] = f2bf(r);
                    else
                        ((float*)Cv)[(size_t)row * Nlog + col] = r;
                }
            }
        }
    }
}

// ---------------------------------------------------------------------------
// GAT aggregate (round-16 proven alternating loop): one wave per block, two
// consecutive nodes per wave, compute/refill alternation. bf16 xlr gather,
// scalarized CSR walk, base-2 no-max softmax, DPP reduce, XCD swizzle.
// ---------------------------------------------------------------------------
__global__ __launch_bounds__(64) void gat_agg(const unsigned short* __restrict__ xlr,
                                              const int* __restrict__ rowptr,
                                              const int* __restrict__ csrcB,
                                              const float* __restrict__ att,
                                              const float* __restrict__ bias,
                                              const float* __restrict__ lng,
                                              const float* __restrict__ lnb,
                                              float* __restrict__ h,
                                              unsigned short* __restrict__ hh) {
    int cpx = gridDim.x >> 3;
    int swz = (blockIdx.x & 7) * cpx + (blockIdx.x >> 3);
    int lane = threadIdx.x;
    int na = __builtin_amdgcn_readfirstlane(swz * 2);
    int nb_ = na + 1;
    int voff = lane * 8;                      // byte offset (4 bf16/lane)

    ushort4 ua = *reinterpret_cast<const ushort4*>(xlr + (size_t)na * 512 + 256 + lane * 4);
    ushort4 ub = *reinterpret_cast<const ushort4*>(xlr + (size_t)nb_ * 512 + 256 + lane * 4);
    float xa0 = bf2f(ua.x), xa1 = bf2f(ua.y), xa2 = bf2f(ua.z), xa3 = bf2f(ua.w);
    float xb0 = bf2f(ub.x), xb1 = bf2f(ub.y), xb2 = bf2f(ub.z), xb3 = bf2f(ub.w);
    float4 at4 = *reinterpret_cast<const float4*>(att + lane * 4);
    at4.x *= LOG2E; at4.y *= LOG2E; at4.z *= LOG2E; at4.w *= LOG2E;

    int e0a = __builtin_amdgcn_readfirstlane(rowptr[na]);
    int e1a = __builtin_amdgcn_readfirstlane(rowptr[na + 1]);
    int e1b = __builtin_amdgcn_readfirstlane(rowptr[nb_ + 1]);
    int e0b = e1a;   // consecutive nodes, contiguous CSR

    float sA = 0.f, aA0 = 0.f, aA1 = 0.f, aA2 = 0.f, aA3 = 0.f;
    float sB = 0.f, aB0 = 0.f, aB1 = 0.f, aB2 = 0.f, aB3 = 0.f;
    const char* xB = (const char*)xlr;

    auto ld4 = [&](ushort4* X, int eb, int last) {
        if (eb + 3 <= last) {
            #pragma unroll
            for (int j = 0; j < 4; ++j) {
                int f = csrcB[eb + j];
                X[j] = *reinterpret_cast<const ushort4*>(xB + (unsigned)f + voff);
            }
        } else {
            #pragma unroll
            for (int j = 0; j < 4; ++j) {
                int f = csrcB[min(eb + j, last)];
                X[j] = *reinterpret_cast<const ushort4*>(xB + (unsigned)f + voff);
            }
        }
    };
    auto group4 = [&](const ushort4* X, int eb, int e1,
                      float xr0, float xr1, float xr2, float xr3,
                      float& s_r, float& a0, float& a1, float& a2, float& a3) {
        float xf[4][4];
        #pragma unroll
        for (int j = 0; j < 4; ++j) {
            xf[j][0] = bf2f(X[j].x);
            xf[j][1] = bf2f(X[j].y);
            xf[j][2] = bf2f(X[j].z);
            xf[j][3] = bf2f(X[j].w);
        }
        float p[4];
        #pragma unroll
        for (int j = 0; j < 4; ++j) {
            float z, pp = 0.f;
            z = xf[j][0] + xr0; z = fmaxf(z, 0.2f * z); pp += z * at4.x;
            z = xf[j][1] + xr1; z = fmaxf(z, 0.2f * z); pp += z * at4.y;
            z = xf[j][2] + xr2; z = fmaxf(z, 0.2f * z); pp += z * at4.z;
            z = xf[j][3] + xr3; z = fmaxf(z, 0.2f * z); pp += z * at4.w;
            p[j] = grp8_sum(pp);
        }
        float w[4];
        if (eb + 3 < e1) {
            #pragma unroll
            for (int j = 0; j < 4; ++j) w[j] = fexp2(fminf(p[j], 80.f));
        } else {
            #pragma unroll
            for (int j = 0; j < 4; ++j) {
                float pc = (eb + j < e1) ? fminf(p[j], 80.f) : -INFINITY;
                w[j] = fexp2(pc);
            }
        }
        s_r += (w[0] + w[1]) + (w[2] + w[3]);
        #pragma unroll
        for (int j = 0; j < 4; ++j) {
            a0 += w[j] * xf[j][0];
            a1 += w[j] * xf[j][1];
            a2 += w[j] * xf[j][2];
            a3 += w[j] * xf[j][3];
        }
    };

    ushort4 A[4], B[4], T[4];
    int eA = e0a, eB = e0b;
    ld4(A, eA, e1a - 1);
    ld4(B, eB, e1b - 1);
    while (eA < e1a || eB < e1b) {
        if (eA < e1a) {
            #pragma unroll
            for (int j = 0; j < 4; ++j) T[j] = A[j];
            if (eA + 4 < e1a) ld4(A, eA + 4, e1a - 1);
            group4(T, eA, e1a, xa0, xa1, xa2, xa3, sA, aA0, aA1, aA2, aA3);
            eA += 4;
        }
        if (eB < e1b) {
            #pragma unroll
            for (int j = 0; j < 4; ++j) T[j] = B[j];
            if (eB + 4 < e1b) ld4(B, eB + 4, e1b - 1);
            group4(T, eB, e1b, xb0, xb1, xb2, xb3, sB, aB0, aB1, aB2, aB3);
            eB += 4;
        }
    }

    auto finish = [&](int n, float s_r, float a0, float a1, float a2, float a3) {
        float inv = 1.f / s_r;
        float4 hr4 = *reinterpret_cast<const float4*>(h + (size_t)n * CN + lane * 4);
        float4 bi4 = *reinterpret_cast<const float4*>(bias + lane * 4);
        float v0 = hr4.x + fmaxf(a0 * inv + bi4.x, 0.f);
        float v1 = hr4.y + fmaxf(a1 * inv + bi4.y, 0.f);
        float v2 = hr4.z + fmaxf(a2 * inv + bi4.z, 0.f);
        float v3 = hr4.w + fmaxf(a3 * inv + bi4.w, 0.f);
        float sum = v0 + v1 + v2 + v3;
        float sq = v0 * v0 + v1 * v1 + v2 * v2 + v3 * v3;
        #pragma unroll
        for (int o = 32; o; o >>= 1) { sum += __shfl_xor(sum, o); sq += __shfl_xor(sq, o); }
        float mu = sum / CN;
        float var = sq / CN - mu * mu;
        float ninv = rsqrtf(var + 1e-5f);
        float4 lg4 = *reinterpret_cast<const float4*>(lng + lane * 4);
        float4 lb4 = *reinterpret_cast<const float4*>(lnb + lane * 4);
        float o0 = (v0 - mu) * ninv * lg4.x + lb4.x;
        float o1 = (v1 - mu) * ninv * lg4.y + lb4.y;
        float o2 = (v2 - mu) * ninv * lg4.z + lb4.z;
        float o3 = (v3 - mu) * ninv * lg4.w + lb4.w;
        *reinterpret_cast<float4*>(h + (size_t)n * CN + lane * 4) = make_float4(o0, o1, o2, o3);
        ushort4 uh;
        uh.x = f2bf(o0); uh.y = f2bf(o1); uh.z = f2bf(o2); uh.w = f2bf(o3);
        *reinterpret_cast<ushort4*>(hh + (size_t)n * CN + lane * 4) = uh;
    };
    finish(na, sA, aA0, aA1, aA2, aA3);
    finish(nb_, sB, aB0, aB1, aB2, aB3);
}

// ---------------------------------------------------------------------------
// gate[n] = relu(gtmp[n]) . gW2 + gb2
// ---------------------------------------------------------------------------
__global__ __launch_bounds__(256) void gate2_kernel(const float* __restrict__ gtmp,
                                                    const float* __restrict__ gW2,
                                                    const float* __restrict__ gb2,
                                                    float* __restrict__ gate, int N) {
    int n = blockIdx.x * 4 + (threadIdx.x >> 6);
    if (n >= N) return;
    int lane = threadIdx.x & 63;
    float2 t = *reinterpret_cast<const float2*>(gtmp + (size_t)n * GATE_DIM + lane * 2);
    float2 w = *reinterpret_cast<const float2*>(gW2 + lane * 2);
    float c = fmaxf(t.x, 0.f) * w.x + fmaxf(t.y, 0.f) * w.y;
    #pragma unroll
    for (int o = 32; o; o >>= 1) c += __shfl_xor(c, o);
    if (lane == 0) gate[n] = c + gb2[0];
}

// ---------------------------------------------------------------------------
// Pool: segment softmax over contiguous 88-node graphs + weighted sum -> emb
// ---------------------------------------------------------------------------
__global__ __launch_bounds__(256) void pool_kernel(const float* __restrict__ gate,
                                                   const float* __restrict__ h,
                                                   float* __restrict__ emb) {
    __shared__ float a[KPG];
    __shared__ float wm[4];
    int g = blockIdx.x, tid = threadIdx.x;
    int wid = tid >> 6, lane = tid & 63;
    float gv = (tid < KPG) ? gate[g * KPG + tid] : -INFINITY;
    float m = gv;
    #pragma unroll
    for (int o = 32; o; o >>= 1) m = fmaxf(m, __shfl_xor(m, o));
    if (lane == 0) wm[wid] = m;
    __syncthreads();
    m = fmaxf(fmaxf(wm[0], wm[1]), fmaxf(wm[2], wm[3]));
    __syncthreads();
    float av = (tid < KPG) ? expf(gv - m) : 0.f;
    if (tid < KPG) a[tid] = av;
    float s = av;
    #pragma unroll
    for (int o = 32; o; o >>= 1) s += __shfl_xor(s, o);
    if (lane == 0) wm[wid] = s;
    __syncthreads();
    s = wm[0] + wm[1] + wm[2] + wm[3];
    float inv = 1.f / s;
    float acc = 0.f;
    const float* hg = h + (size_t)g * KPG * CN;
    for (int i = 0; i < KPG; ++i) acc += a[i] * hg[i * CN + tid];
    emb[(size_t)g * CN + tid] = acc * inv;
}

// ---------------------------------------------------------------------------
// Heads: t1 = relu(LN(emb@pW1+pb1)) (bf16 hi/lo out); value head full
// ---------------------------------------------------------------------------
__global__ __launch_bounds__(256) void head_kernel(const float* __restrict__ emb,
    const float* __restrict__ pW1, const float* __restrict__ pb1,
    const float* __restrict__ plng, const float* __restrict__ plnb,
    const float* __restrict__ vW1, const float* __restrict__ vb1,
    const float* __restrict__ vW2, const float* __restrict__ vb2,
    unsigned short* __restrict__ t1h, unsigned short* __restrict__ t1l,
    float* __restrict__ value_out) {
    __shared__ float e_l[CN];
    __shared__ float rsum[4], rsq[4];
    int g = blockIdx.x, tid = threadIdx.x;
    int wid = tid >> 6, lane = tid & 63;
    e_l[tid] = emb[(size_t)g * CN + tid];
    __syncthreads();
    float p = pb1[tid], v = vb1[tid];
    for (int k = 0; k < CN; ++k) {
        float e = e_l[k];
        p += e * pW1[k * CN + tid];
        v += e * vW1[k * CN + tid];
    }
    float sum = p, sq = p * p;
    #pragma unroll
    for (int o = 32; o; o >>= 1) { sum += __shfl_xor(sum, o); sq += __shfl_xor(sq, o); }
    if (lane == 0) { rsum[wid] = sum; rsq[wid] = sq; }
    __syncthreads();
    sum = rsum[0] + rsum[1] + rsum[2] + rsum[3];
    sq  = rsq[0] + rsq[1] + rsq[2] + rsq[3];
    float mu = sum / CN;
    float var = sq / CN - mu * mu;
    float inv = rsqrtf(var + 1e-5f);
    float t1v = fmaxf((p - mu) * inv * plng[tid] + plnb[tid], 0.f);
    unsigned short th = f2bf(t1v);
    t1h[(size_t)g * CN + tid] = th;
    t1l[(size_t)g * CN + tid] = f2bf(t1v - bf2f(th));
    float contrib = fmaxf(v, 0.f) * vW2[tid];
    __syncthreads();
    #pragma unroll
    for (int o = 32; o; o >>= 1) contrib += __shfl_xor(contrib, o);
    if (lane == 0) rsum[wid] = contrib;
    __syncthreads();
    if (tid == 0)
        value_out[g] = tanhf(rsum[0] + rsum[1] + rsum[2] + rsum[3] + vb2[0]);
}

// ---------------------------------------------------------------------------
extern "C" void kernel_launch(void* const* d_in, const int* in_sizes, int n_in,
                              void* d_out, int out_size, void* d_ws, size_t ws_size,
                              hipStream_t stream) {
    const float* x        = (const float*)d_in[0];
    const int*   ei       = (const int*)d_in[1];
    const float* W_emb    = (const float*)d_in[4];
    const float* b_emb    = (const float*)d_in[5];
    const float* pos_emb  = (const float*)d_in[6];
    const float* gat_Wsrc = (const float*)d_in[7];
    const float* gat_Wdst = (const float*)d_in[8];
    const float* gat_att  = (const float*)d_in[9];
    const float* gat_bias = (const float*)d_in[10];
    const float* ln_g     = (const float*)d_in[11];
    const float* ln_b     = (const float*)d_in[12];
    const float* gW1      = (const float*)d_in[13];
    const float* gb1      = (const float*)d_in[14];
    const float* gW2      = (const float*)d_in[15];
    const float* gb2      = (const float*)d_in[16];
    const float* pW1      = (const float*)d_in[17];
    const float* pb1      = (const float*)d_in[18];
    const float* p_ln_g   = (const float*)d_in[19];
    const float* p_ln_b   = (const float*)d_in[20];
    const float* pW2      = (const float*)d_in[21];
    const float* pb2      = (const float*)d_in[22];
    const float* vW1      = (const float*)d_in[23];
    const float* vb1      = (const float*)d_in[24];
    const float* vW2      = (const float*)d_in[25];
    const float* vb2      = (const float*)d_in[26];

    const int N = in_sizes[2];      // 22528
    const int E = in_sizes[1] / 2;  // 405504
    const int G = N / KPG;          // 256
    const int NB_SC = (N + 1023) / 1024;

    const int NB_CAT = 32;                        // 512/16
    const int NB_G1  = 8;                         // 128/16
    const int GY_POL = (ACT_DIM + 63) / 64;       // 73 (BN=64 tiles)
    const int NB_POL = GY_POL * 4;                // 292
    const int RPX    = (N / 128) / 8;             // 22 row-blocks per XCD

    char* ws = (char*)d_ws;
    size_t off = 0;
    auto alloc = [&](size_t nbytes) {
        void* pp = ws + off;
        off = (off + nbytes + 255) & ~(size_t)255;
        return pp;
    };
    float* h      = (float*)alloc((size_t)N * CN * 4);
    unsigned short* hh = (unsigned short*)alloc((size_t)N * CN * 2);
    unsigned short* xlr = (unsigned short*)alloc((size_t)N * 512 * 2);   // bf16
    float* gtmp   = (float*)alloc((size_t)N * GATE_DIM * 4);
    unsigned short* WcatH = (unsigned short*)alloc((size_t)4 * 8 * NB_CAT * 512 * 2);
    unsigned short* gW1H  = (unsigned short*)alloc((size_t)8 * NB_G1 * 512 * 2);
    unsigned short* pW2H  = (unsigned short*)alloc((size_t)8 * NB_POL * 512 * 2);
    unsigned short* pW2L  = (unsigned short*)alloc((size_t)8 * NB_POL * 512 * 2);
    float* gate   = (float*)alloc((size_t)N * 4);
    float* emb    = (float*)alloc((size_t)G * CN * 4);
    unsigned short* t1h = (unsigned short*)alloc((size_t)G * CN * 2);
    unsigned short* t1l = (unsigned short*)alloc((size_t)G * CN * 2);
    int*   rowptr = (int*)alloc((size_t)(N + 1) * 4);
    int*   cnt    = (int*)alloc((size_t)N * 4);
    int*   cursor = (int*)alloc((size_t)N * 4);
    int*   btot   = (int*)alloc((size_t)64 * 4);
    int*   csrcB  = (int*)alloc((size_t)E * 4);

    const int* e_src = ei;
    const int* e_dst = ei + E;

    hipMemsetAsync(cnt, 0, (size_t)N * 4, stream);
    hipMemsetAsync(cursor, 0, (size_t)N * 4, stream);
    count_kernel<<<(E + 255) / 256, 256, 0, stream>>>(e_dst, cnt, E);
    scan1_kernel<<<NB_SC, 1024, 0, stream>>>(cnt, rowptr, btot, N);
    scan3_kernel<<<(N + 1024) / 1024, 1024, 0, stream>>>(rowptr, btot, N, NB_SC);
    fill_kernel<<<(E + 255) / 256, 256, 0, stream>>>(e_src, e_dst, rowptr, cursor, csrcB, E);

    embed_kernel<<<N / 16, 256, 0, stream>>>(x, W_emb, b_emb, pos_emb, h, hh);

    {
        int totc = 8 * NB_CAT * 512;
        dim3 gw((totc + 255) / 256, 4);
        wconv_cat_h_kernel<<<gw, 256, 0, stream>>>(gat_Wsrc, gat_Wdst, WcatH, NB_CAT, totc);
        int totg = 8 * NB_G1 * 512;
        wconv_h_kernel<<<(totg + 255) / 256, 256, 0, stream>>>(gW1, gW1H, GATE_DIM, NB_G1, totg);
        int totp = 8 * NB_POL * 512;
        wconv_kernel<<<(totp + 255) / 256, 256, 0, stream>>>(pW2, pW2H, pW2L, ACT_DIM, NB_POL, totp);
    }

    for (int l = 0; l < 4; ++l) {
        size_t wo = (size_t)l * 8 * NB_CAT * 512;
        // XCD-aligned 1D grid: 176 row-blocks x 4 col-blocks = 704 blocks
        mgemm<false, 1, true, 8, true><<<(N / 128) * 4, 256, 0, stream>>>(
            hh, nullptr, WcatH + wo, nullptr, nullptr, xlr, N, 512, NB_CAT, CN, RPX);
        gat_agg<<<N / 2, 64, 0, stream>>>(xlr, rowptr, csrcB, gat_att + l * CN,
                                          gat_bias + l * CN, ln_g + l * CN, ln_b + l * CN,
                                          h, hh);
    }

    // gate MLP (XCD-aligned too: 176 blocks, gy=1)
    {
        mgemm<true, 1, false, 8, true><<<N / 128, 256, 0, stream>>>(
            hh, nullptr, gW1H, nullptr, gb1, gtmp, N, GATE_DIM, NB_G1, CN, RPX);
        gate2_kernel<<<(N + 3) / 4, 256, 0, stream>>>(gtmp, gW2, gb2, gate, N);
    }
    pool_kernel<<<G, 256, 0, stream>>>(gate, h, emb);

    float* policy = (float*)d_out;
    float* value  = (float*)d_out + (size_t)G * ACT_DIM;
    head_kernel<<<G, 256, 0, stream>>>(emb, pW1, pb1, p_ln_g, p_ln_b,
                                       vW1, vb1, vW2, vb2, t1h, t1l, value);
    dim3 g2(G / 128, GY_POL);
    mgemm<true, 3, false, 4, false><<<g2, 256, 0, stream>>>(t1h, t1l, pW2H, pW2L, pb2,
                                                            policy, G, ACT_DIM, NB_POL, CN, 0);
}

// Round 19
// 277.996 us; speedup vs baseline: 1.0518x; 1.0234x over previous
//
#include <hip/hip_runtime.h>
#include <math.h>

constexpr int CN = 256;        // channels
constexpr int NHEAD = 8;       // attention heads
constexpr int KPG = 88;        // nodes per graph
constexpr int NIDF = 16;       // input node features
constexpr int GATE_DIM = 128;
constexpr int ACT_DIM = 4644;
constexpr float LOG2E = 1.4426950408889634f;

typedef __attribute__((ext_vector_type(8))) short bf16x8;
typedef __attribute__((ext_vector_type(4))) float f32x4;

__device__ __forceinline__ unsigned short f2bf(float f) {
    unsigned int u = __float_as_uint(f);
    unsigned int r = (u + 0x7fffu + ((u >> 16) & 1u)) >> 16;
    return (unsigned short)r;
}
__device__ __forceinline__ float bf2f(unsigned short h) {
    return __uint_as_float(((unsigned int)h) << 16);
}

__device__ __forceinline__ void glds16(const void* g, void* l) {
    __builtin_amdgcn_global_load_lds(
        (const __attribute__((address_space(1))) unsigned int*)g,
        (__attribute__((address_space(3))) unsigned int*)l, 16, 0, 0);
}

// raw v_exp_f32: w = 2^x  (inputs pre-scaled by log2e; clamped <= 80, -inf -> 0)
__device__ __forceinline__ float fexp2(float x) {
    float r;
    asm("v_exp_f32 %0, %1" : "=v"(r) : "v"(x));
    return r;
}

// 8-lane group sum via DPP (VALU-speed, no LDS pipe)
__device__ __forceinline__ float grp8_sum(float p) {
    int t;
    t = __builtin_amdgcn_mov_dpp(__float_as_int(p), 0xB1, 0xF, 0xF, true);
    p += __int_as_float(t);
    t = __builtin_amdgcn_mov_dpp(__float_as_int(p), 0x4E, 0xF, 0xF, true);
    p += __int_as_float(t);
    t = __builtin_amdgcn_mov_dpp(__float_as_int(p), 0x141, 0xF, 0xF, true);
    p += __int_as_float(t);
    return p;
}

// ---------------------------------------------------------------------------
// CSR build: count -> scan (2 kernels) -> fill (csrcB = byte offsets)
// ---------------------------------------------------------------------------
__global__ void count_kernel(const int* __restrict__ dst, int* __restrict__ cnt, int E) {
    int e = blockIdx.x * 256 + threadIdx.x;
    if (e < E) atomicAdd(&cnt[dst[e]], 1);
}

__global__ __launch_bounds__(1024) void scan1_kernel(const int* __restrict__ cnt,
                                                     int* __restrict__ rowptr,
                                                     int* __restrict__ btot, int n) {
    __shared__ int buf[1024];
    int tid = threadIdx.x;
    int i = blockIdx.x * 1024 + tid;
    int v = (i < n) ? cnt[i] : 0;
    buf[tid] = v;
    __syncthreads();
    for (int off = 1; off < 1024; off <<= 1) {
        int t = (tid >= off) ? buf[tid - off] : 0;
        __syncthreads();
        buf[tid] += t;
        __syncthreads();
    }
    if (i < n) rowptr[i] = buf[tid] - v;
    if (tid == 1023) btot[blockIdx.x] = buf[1023];
}

// adds prefix of btot inline (nb <= 32, each thread sums serially)
__global__ __launch_bounds__(1024) void scan3_kernel(int* __restrict__ rowptr,
                                                     const int* __restrict__ btot,
                                                     int n, int nb) {
    int i = blockIdx.x * 1024 + threadIdx.x;
    int b = i >> 10;
    if (i < n) {
        int pre = 0;
        for (int k = 0; k < b; ++k) pre += btot[k];
        rowptr[i] += pre;
    } else if (i == n) {
        int pre = 0;
        for (int k = 0; k < nb; ++k) pre += btot[k];
        rowptr[n] = pre;
    }
}

__global__ void fill_kernel(const int* __restrict__ src, const int* __restrict__ dst,
                            const int* __restrict__ rowptr, int* __restrict__ cursor,
                            int* __restrict__ csrcB, int E) {
    int e = blockIdx.x * 256 + threadIdx.x;
    if (e < E) {
        int d = dst[e];
        int p = atomicAdd(&cursor[d], 1);
        csrcB[rowptr[d] + p] = src[e] * 1024;   // byte offset into bf16 xlr (512 bf16/row)
    }
}

// ---------------------------------------------------------------------------
// Embedding: hh = bf16(relu(x @ W_emb + b_emb) + pos_emb[n % 88])
// ---------------------------------------------------------------------------
__global__ __launch_bounds__(256) void embed_kernel(const float* __restrict__ x,
                                                    const float* __restrict__ Wemb,
                                                    const float* __restrict__ bemb,
                                                    const float* __restrict__ pos,
                                                    unsigned short* __restrict__ hh) {
    __shared__ float Wl[NIDF][CN];
    int tid = threadIdx.x;
    for (int i = tid; i < NIDF * CN; i += 256) Wl[i >> 8][i & 255] = Wemb[i];
    __syncthreads();
    float bias = bemb[tid];
    int node0 = blockIdx.x * 16;
    for (int q = 0; q < 16; ++q) {
        int n = node0 + q;
        float acc = bias;
        #pragma unroll
        for (int k = 0; k < NIDF; ++k) acc += x[n * NIDF + k] * Wl[k][tid];
        float val = fmaxf(acc, 0.f) + pos[(n % KPG) * CN + tid];
        hh[(size_t)n * CN + tid] = f2bf(val);
    }
}

// ---------------------------------------------------------------------------
// Weight relayout kernels. *_h variants emit bf16 hi only (for PROD=1 GEMMs).
// ---------------------------------------------------------------------------
__global__ void wconv_cat_h_kernel(const float* __restrict__ Ws, const float* __restrict__ Wd,
                                   unsigned short* __restrict__ Bh, int NB, int tot) {
    int o = blockIdx.x * 256 + threadIdx.x;
    if (o >= tot) return;
    int l4 = blockIdx.y;
    const float* ws = Ws + (size_t)l4 * 256 * 256;
    const float* wd = Wd + (size_t)l4 * 256 * 256;
    int idx = o & 511;
    int nb = (o >> 9) % NB;
    int kb = o / (512 * NB);
    int l = idx >> 3, j = idx & 7;
    int k = kb * 32 + (l >> 4) * 8 + j;
    int c = nb * 16 + (l & 15);
    float v = (c < 256) ? ws[(size_t)k * 256 + c] : wd[(size_t)k * 256 + (c - 256)];
    Bh[(size_t)l4 * tot + o] = f2bf(v);
}

__global__ void wconv_h_kernel(const float* __restrict__ W, unsigned short* __restrict__ Bh,
                               int Nn, int NB, int tot) {
    int o = blockIdx.x * 256 + threadIdx.x;
    if (o >= tot) return;
    int idx = o & 511;
    int nb = (o >> 9) % NB;
    int kb = o / (512 * NB);
    int l = idx >> 3, j = idx & 7;
    int k = kb * 32 + (l >> 4) * 8 + j;
    int c = nb * 16 + (l & 15);
    float v = (c < Nn) ? W[(size_t)k * Nn + c] : 0.f;
    Bh[o] = f2bf(v);
}

__global__ void wconv_kernel(const float* __restrict__ W, unsigned short* __restrict__ Bh,
                             unsigned short* __restrict__ Bl, int Nn, int NB, int tot) {
    int o = blockIdx.x * 256 + threadIdx.x;
    if (o >= tot) return;
    int idx = o & 511;
    int nb = (o >> 9) % NB;
    int kb = o / (512 * NB);
    int l = idx >> 3, j = idx & 7;
    int k = kb * 32 + (l >> 4) * 8 + j;
    int c = nb * 16 + (l & 15);
    float v = (c < Nn) ? W[(size_t)k * Nn + c] : 0.f;
    unsigned short hh = f2bf(v);
    Bh[o] = hh;
    Bl[o] = f2bf(v - bf2f(hh));
}

// ---------------------------------------------------------------------------
// MFMA GEMM, bf16 split: C = A @ B (+bias).
// PROD=1: AhBh only. PROD=2: +AhBl. PROD=3: +AlBh.
// OBF16 : emit C as bf16.  NBT: B-tile width in 16-col blocks.
// XSWZ  : 1D grid, XCD-aligned decomposition.
// ---------------------------------------------------------------------------
template <bool BIAS, int PROD, bool OBF16, int NBT, bool XSWZ>
__global__ __launch_bounds__(256) void mgemm(const unsigned short* __restrict__ Ah,
                                             const unsigned short* __restrict__ Al,
                                             const unsigned short* __restrict__ Bh,
                                             const unsigned short* __restrict__ Bl,
                                             const float* __restrict__ bias,
                                             void* __restrict__ Cv,
                                             int M, int Nlog, int NB, int K, int RPX) {
    constexpr int NF = NBT / 2;           // per-wave N fragments
    __shared__ unsigned short AhL[8 * 64 * 8];
    __shared__ unsigned short AlL[(PROD >= 3) ? 8 * 64 * 8 : 16];
    __shared__ unsigned short BhL[NBT * 512];
    __shared__ unsigned short BlL[(PROD >= 2) ? NBT * 512 : 16];
    int tid = threadIdx.x;
    int wid = tid >> 6, lane = tid & 63;
    int bx, cb;
    if constexpr (XSWZ) {
        int b = blockIdx.x;
        int xcd = b & 7;
        int i = b >> 3;
        bx = xcd * RPX + i % RPX;
        cb = i / RPX;
    } else {
        bx = blockIdx.x;
        cb = blockIdx.y;
    }
    int row0 = bx * 128;
    int wr = wid >> 1, wc = wid & 1;

    int rr = lane & 15, kq = lane >> 4;

    f32x4 acc[4][NF] = {};

    for (int k0 = 0; k0 < K; k0 += 32) {
        int kb = k0 >> 5;
        {
            int mb0 = wid * 2;
            const unsigned short* s0 = Ah + (size_t)(row0 + mb0 * 16 + rr) * K + k0 + kq * 8;
            const unsigned short* s1 = Ah + (size_t)(row0 + mb0 * 16 + 16 + rr) * K + k0 + kq * 8;
            glds16(s0, &AhL[mb0 * 512]);
            glds16(s1, &AhL[mb0 * 512 + 512]);
            if constexpr (PROD >= 3) {
                const unsigned short* t0 = Al + (size_t)(row0 + mb0 * 16 + rr) * K + k0 + kq * 8;
                const unsigned short* t1 = Al + (size_t)(row0 + mb0 * 16 + 16 + rr) * K + k0 + kq * 8;
                glds16(t0, &AlL[mb0 * 512]);
                glds16(t1, &AlL[mb0 * 512 + 512]);
            }
        }
        {
            size_t base = ((size_t)kb * NB + (size_t)cb * NBT) * 512;
            for (int ch = wid; ch < NBT; ch += 4) {
                glds16(Bh + base + ch * 512 + lane * 8, &BhL[ch * 512]);
                if constexpr (PROD >= 2)
                    glds16(Bl + base + ch * 512 + lane * 8, &BlL[ch * 512]);
            }
        }
        __syncthreads();
        bf16x8 a_h[4], a_l[4], b_h[NF], b_l[NF];
        #pragma unroll
        for (int mf = 0; mf < 4; ++mf) {
            int off = ((wr * 4 + mf) * 64 + lane) * 8;
            a_h[mf] = *reinterpret_cast<const bf16x8*>(&AhL[off]);
            if constexpr (PROD >= 3)
                a_l[mf] = *reinterpret_cast<const bf16x8*>(&AlL[off]);
        }
        #pragma unroll
        for (int nf = 0; nf < NF; ++nf) {
            int off = ((wc * NF + nf) * 64 + lane) * 8;
            b_h[nf] = *reinterpret_cast<const bf16x8*>(&BhL[off]);
            if constexpr (PROD >= 2)
                b_l[nf] = *reinterpret_cast<const bf16x8*>(&BlL[off]);
        }
        #pragma unroll
        for (int mf = 0; mf < 4; ++mf)
            #pragma unroll
            for (int nf = 0; nf < NF; ++nf) {
                acc[mf][nf] = __builtin_amdgcn_mfma_f32_16x16x32_bf16(a_h[mf], b_h[nf], acc[mf][nf], 0, 0, 0);
                if constexpr (PROD >= 2)
                    acc[mf][nf] = __builtin_amdgcn_mfma_f32_16x16x32_bf16(a_h[mf], b_l[nf], acc[mf][nf], 0, 0, 0);
                if constexpr (PROD >= 3)
                    acc[mf][nf] = __builtin_amdgcn_mfma_f32_16x16x32_bf16(a_l[mf], b_h[nf], acc[mf][nf], 0, 0, 0);
            }
        __syncthreads();
    }
    #pragma unroll
    for (int mf = 0; mf < 4; ++mf) {
        #pragma unroll
        for (int nf = 0; nf < NF; ++nf) {
            int col = cb * (NBT * 16) + wc * (NF * 16) + nf * 16 + (lane & 15);
            if (col < Nlog) {
                float bv = BIAS ? bias[col] : 0.f;
                #pragma unroll
                for (int rg = 0; rg < 4; ++rg) {
                    int row = row0 + wr * 64 + mf * 16 + (lane >> 4) * 4 + rg;
                    float r = acc[mf][nf][rg] + bv;
                    if constexpr (OBF16)
                        ((unsigned short*)Cv)[(size_t)row * Nlog + col] = f2bf(r);
                    else
                        ((float*)Cv)[(size_t)row * Nlog + col] = r;
                }
            }
        }
    }
}

// ---------------------------------------------------------------------------
// GAT aggregate v15: residual + output both in bf16 hh (no fp32 h buffer).
// One wave per block, two consecutive nodes per wave, compute/refill
// alternation, bf16 xlr gather, scalarized CSR walk, base-2 no-max softmax,
// DPP reduce, XCD swizzle.
// ---------------------------------------------------------------------------
__global__ __launch_bounds__(64) void gat_agg(const unsigned short* __restrict__ xlr,
                                              const int* __restrict__ rowptr,
                                              const int* __restrict__ csrcB,
                                              const float* __restrict__ att,
                                              const float* __restrict__ bias,
                                              const float* __restrict__ lng,
                                              const float* __restrict__ lnb,
                                              unsigned short* __restrict__ hh) {
    int cpx = gridDim.x >> 3;
    int swz = (blockIdx.x & 7) * cpx + (blockIdx.x >> 3);
    int lane = threadIdx.x;
    int na = __builtin_amdgcn_readfirstlane(swz * 2);
    int nb_ = na + 1;
    int voff = lane * 8;                      // byte offset (4 bf16/lane)

    ushort4 ua = *reinterpret_cast<const ushort4*>(xlr + (size_t)na * 512 + 256 + lane * 4);
    ushort4 ub = *reinterpret_cast<const ushort4*>(xlr + (size_t)nb_ * 512 + 256 + lane * 4);
    float xa0 = bf2f(ua.x), xa1 = bf2f(ua.y), xa2 = bf2f(ua.z), xa3 = bf2f(ua.w);
    float xb0 = bf2f(ub.x), xb1 = bf2f(ub.y), xb2 = bf2f(ub.z), xb3 = bf2f(ub.w);
    float4 at4 = *reinterpret_cast<const float4*>(att + lane * 4);
    at4.x *= LOG2E; at4.y *= LOG2E; at4.z *= LOG2E; at4.w *= LOG2E;

    int e0a = __builtin_amdgcn_readfirstlane(rowptr[na]);
    int e1a = __builtin_amdgcn_readfirstlane(rowptr[na + 1]);
    int e1b = __builtin_amdgcn_readfirstlane(rowptr[nb_ + 1]);
    int e0b = e1a;   // consecutive nodes, contiguous CSR

    float sA = 0.f, aA0 = 0.f, aA1 = 0.f, aA2 = 0.f, aA3 = 0.f;
    float sB = 0.f, aB0 = 0.f, aB1 = 0.f, aB2 = 0.f, aB3 = 0.f;
    const char* xB = (const char*)xlr;

    auto ld4 = [&](ushort4* X, int eb, int last) {
        if (eb + 3 <= last) {
            #pragma unroll
            for (int j = 0; j < 4; ++j) {
                int f = csrcB[eb + j];
                X[j] = *reinterpret_cast<const ushort4*>(xB + (unsigned)f + voff);
            }
        } else {
            #pragma unroll
            for (int j = 0; j < 4; ++j) {
                int f = csrcB[min(eb + j, last)];
                X[j] = *reinterpret_cast<const ushort4*>(xB + (unsigned)f + voff);
            }
        }
    };
    auto group4 = [&](const ushort4* X, int eb, int e1,
                      float xr0, float xr1, float xr2, float xr3,
                      float& s_r, float& a0, float& a1, float& a2, float& a3) {
        float xf[4][4];
        #pragma unroll
        for (int j = 0; j < 4; ++j) {
            xf[j][0] = bf2f(X[j].x);
            xf[j][1] = bf2f(X[j].y);
            xf[j][2] = bf2f(X[j].z);
            xf[j][3] = bf2f(X[j].w);
        }
        float p[4];
        #pragma unroll
        for (int j = 0; j < 4; ++j) {
            float z, pp = 0.f;
            z = xf[j][0] + xr0; z = fmaxf(z, 0.2f * z); pp += z * at4.x;
            z = xf[j][1] + xr1; z = fmaxf(z, 0.2f * z); pp += z * at4.y;
            z = xf[j][2] + xr2; z = fmaxf(z, 0.2f * z); pp += z * at4.z;
            z = xf[j][3] + xr3; z = fmaxf(z, 0.2f * z); pp += z * at4.w;
            p[j] = grp8_sum(pp);
        }
        float w[4];
        if (eb + 3 < e1) {
            #pragma unroll
            for (int j = 0; j < 4; ++j) w[j] = fexp2(fminf(p[j], 80.f));
        } else {
            #pragma unroll
            for (int j = 0; j < 4; ++j) {
                float pc = (eb + j < e1) ? fminf(p[j], 80.f) : -INFINITY;
                w[j] = fexp2(pc);
            }
        }
        s_r += (w[0] + w[1]) + (w[2] + w[3]);
        #pragma unroll
        for (int j = 0; j < 4; ++j) {
            a0 += w[j] * xf[j][0];
            a1 += w[j] * xf[j][1];
            a2 += w[j] * xf[j][2];
            a3 += w[j] * xf[j][3];
        }
    };

    ushort4 A[4], B[4], T[4];
    int eA = e0a, eB = e0b;
    ld4(A, eA, e1a - 1);
    ld4(B, eB, e1b - 1);
    while (eA < e1a || eB < e1b) {
        if (eA < e1a) {
            #pragma unroll
            for (int j = 0; j < 4; ++j) T[j] = A[j];
            if (eA + 4 < e1a) ld4(A, eA + 4, e1a - 1);
            group4(T, eA, e1a, xa0, xa1, xa2, xa3, sA, aA0, aA1, aA2, aA3);
            eA += 4;
        }
        if (eB < e1b) {
            #pragma unroll
            for (int j = 0; j < 4; ++j) T[j] = B[j];
            if (eB + 4 < e1b) ld4(B, eB + 4, e1b - 1);
            group4(T, eB, e1b, xb0, xb1, xb2, xb3, sB, aB0, aB1, aB2, aB3);
            eB += 4;
        }
    }

    auto finish = [&](int n, float s_r, float a0, float a1, float a2, float a3) {
        float inv = 1.f / s_r;
        ushort4 hr = *reinterpret_cast<const ushort4*>(hh + (size_t)n * CN + lane * 4);
        float4 bi4 = *reinterpret_cast<const float4*>(bias + lane * 4);
        float v0 = bf2f(hr.x) + fmaxf(a0 * inv + bi4.x, 0.f);
        float v1 = bf2f(hr.y) + fmaxf(a1 * inv + bi4.y, 0.f);
        float v2 = bf2f(hr.z) + fmaxf(a2 * inv + bi4.z, 0.f);
        float v3 = bf2f(hr.w) + fmaxf(a3 * inv + bi4.w, 0.f);
        float sum = v0 + v1 + v2 + v3;
        float sq = v0 * v0 + v1 * v1 + v2 * v2 + v3 * v3;
        #pragma unroll
        for (int o = 32; o; o >>= 1) { sum += __shfl_xor(sum, o); sq += __shfl_xor(sq, o); }
        float mu = sum / CN;
        float var = sq / CN - mu * mu;
        float ninv = rsqrtf(var + 1e-5f);
        float4 lg4 = *reinterpret_cast<const float4*>(lng + lane * 4);
        float4 lb4 = *reinterpret_cast<const float4*>(lnb + lane * 4);
        float o0 = (v0 - mu) * ninv * lg4.x + lb4.x;
        float o1 = (v1 - mu) * ninv * lg4.y + lb4.y;
        float o2 = (v2 - mu) * ninv * lg4.z + lb4.z;
        float o3 = (v3 - mu) * ninv * lg4.w + lb4.w;
        ushort4 uh;
        uh.x = f2bf(o0); uh.y = f2bf(o1); uh.z = f2bf(o2); uh.w = f2bf(o3);
        *reinterpret_cast<ushort4*>(hh + (size_t)n * CN + lane * 4) = uh;
    };
    finish(na, sA, aA0, aA1, aA2, aA3);
    finish(nb_, sB, aB0, aB1, aB2, aB3);
}

// ---------------------------------------------------------------------------
// gate[n] = relu(gtmp[n]) . gW2 + gb2
// ---------------------------------------------------------------------------
__global__ __launch_bounds__(256) void gate2_kernel(const float* __restrict__ gtmp,
                                                    const float* __restrict__ gW2,
                                                    const float* __restrict__ gb2,
                                                    float* __restrict__ gate, int N) {
    int n = blockIdx.x * 4 + (threadIdx.x >> 6);
    if (n >= N) return;
    int lane = threadIdx.x & 63;
    float2 t = *reinterpret_cast<const float2*>(gtmp + (size_t)n * GATE_DIM + lane * 2);
    float2 w = *reinterpret_cast<const float2*>(gW2 + lane * 2);
    float c = fmaxf(t.x, 0.f) * w.x + fmaxf(t.y, 0.f) * w.y;
    #pragma unroll
    for (int o = 32; o; o >>= 1) c += __shfl_xor(c, o);
    if (lane == 0) gate[n] = c + gb2[0];
}

// ---------------------------------------------------------------------------
// Pool: segment softmax over contiguous 88-node graphs + weighted sum -> emb
// (reads bf16 hh)
// ---------------------------------------------------------------------------
__global__ __launch_bounds__(256) void pool_kernel(const float* __restrict__ gate,
                                                   const unsigned short* __restrict__ hh,
                                                   float* __restrict__ emb) {
    __shared__ float a[KPG];
    __shared__ float wm[4];
    int g = blockIdx.x, tid = threadIdx.x;
    int wid = tid >> 6, lane = tid & 63;
    float gv = (tid < KPG) ? gate[g * KPG + tid] : -INFINITY;
    float m = gv;
    #pragma unroll
    for (int o = 32; o; o >>= 1) m = fmaxf(m, __shfl_xor(m, o));
    if (lane == 0) wm[wid] = m;
    __syncthreads();
    m = fmaxf(fmaxf(wm[0], wm[1]), fmaxf(wm[2], wm[3]));
    __syncthreads();
    float av = (tid < KPG) ? expf(gv - m) : 0.f;
    if (tid < KPG) a[tid] = av;
    float s = av;
    #pragma unroll
    for (int o = 32; o; o >>= 1) s += __shfl_xor(s, o);
    if (lane == 0) wm[wid] = s;
    __syncthreads();
    s = wm[0] + wm[1] + wm[2] + wm[3];
    float inv = 1.f / s;
    float acc = 0.f;
    const unsigned short* hg = hh + (size_t)g * KPG * CN;
    for (int i = 0; i < KPG; ++i) acc += a[i] * bf2f(hg[i * CN + tid]);
    emb[(size_t)g * CN + tid] = acc * inv;
}

// ---------------------------------------------------------------------------
// Heads: t1 = relu(LN(emb@pW1+pb1)) (bf16 hi/lo out); value head full
// ---------------------------------------------------------------------------
__global__ __launch_bounds__(256) void head_kernel(const float* __restrict__ emb,
    const float* __restrict__ pW1, const float* __restrict__ pb1,
    const float* __restrict__ plng, const float* __restrict__ plnb,
    const float* __restrict__ vW1, const float* __restrict__ vb1,
    const float* __restrict__ vW2, const float* __restrict__ vb2,
    unsigned short* __restrict__ t1h, unsigned short* __restrict__ t1l,
    float* __restrict__ value_out) {
    __shared__ float e_l[CN];
    __shared__ float rsum[4], rsq[4];
    int g = blockIdx.x, tid = threadIdx.x;
    int wid = tid >> 6, lane = tid & 63;
    e_l[tid] = emb[(size_t)g * CN + tid];
    __syncthreads();
    float p = pb1[tid], v = vb1[tid];
    for (int k = 0; k < CN; ++k) {
        float e = e_l[k];
        p += e * pW1[k * CN + tid];
        v += e * vW1[k * CN + tid];
    }
    float sum = p, sq = p * p;
    #pragma unroll
    for (int o = 32; o; o >>= 1) { sum += __shfl_xor(sum, o); sq += __shfl_xor(sq, o); }
    if (lane == 0) { rsum[wid] = sum; rsq[wid] = sq; }
    __syncthreads();
    sum = rsum[0] + rsum[1] + rsum[2] + rsum[3];
    sq  = rsq[0] + rsq[1] + rsq[2] + rsq[3];
    float mu = sum / CN;
    float var = sq / CN - mu * mu;
    float inv = rsqrtf(var + 1e-5f);
    float t1v = fmaxf((p - mu) * inv * plng[tid] + plnb[tid], 0.f);
    unsigned short th = f2bf(t1v);
    t1h[(size_t)g * CN + tid] = th;
    t1l[(size_t)g * CN + tid] = f2bf(t1v - bf2f(th));
    float contrib = fmaxf(v, 0.f) * vW2[tid];
    __syncthreads();
    #pragma unroll
    for (int o = 32; o; o >>= 1) contrib += __shfl_xor(contrib, o);
    if (lane == 0) rsum[wid] = contrib;
    __syncthreads();
    if (tid == 0)
        value_out[g] = tanhf(rsum[0] + rsum[1] + rsum[2] + rsum[3] + vb2[0]);
}

// ---------------------------------------------------------------------------
extern "C" void kernel_launch(void* const* d_in, const int* in_sizes, int n_in,
                              void* d_out, int out_size, void* d_ws, size_t ws_size,
                              hipStream_t stream) {
    const float* x        = (const float*)d_in[0];
    const int*   ei       = (const int*)d_in[1];
    const float* W_emb    = (const float*)d_in[4];
    const float* b_emb    = (const float*)d_in[5];
    const float* pos_emb  = (const float*)d_in[6];
    const float* gat_Wsrc = (const float*)d_in[7];
    const float* gat_Wdst = (const float*)d_in[8];
    const float* gat_att  = (const float*)d_in[9];
    const float* gat_bias = (const float*)d_in[10];
    const float* ln_g     = (const float*)d_in[11];
    const float* ln_b     = (const float*)d_in[12];
    const float* gW1      = (const float*)d_in[13];
    const float* gb1      = (const float*)d_in[14];
    const float* gW2      = (const float*)d_in[15];
    const float* gb2      = (const float*)d_in[16];
    const float* pW1      = (const float*)d_in[17];
    const float* pb1      = (const float*)d_in[18];
    const float* p_ln_g   = (const float*)d_in[19];
    const float* p_ln_b   = (const float*)d_in[20];
    const float* pW2      = (const float*)d_in[21];
    const float* pb2      = (const float*)d_in[22];
    const float* vW1      = (const float*)d_in[23];
    const float* vb1      = (const float*)d_in[24];
    const float* vW2      = (const float*)d_in[25];
    const float* vb2      = (const float*)d_in[26];

    const int N = in_sizes[2];      // 22528
    const int E = in_sizes[1] / 2;  // 405504
    const int G = N / KPG;          // 256
    const int NB_SC = (N + 1023) / 1024;

    const int NB_CAT = 32;                        // 512/16
    const int NB_G1  = 8;                         // 128/16
    const int GY_POL = (ACT_DIM + 63) / 64;       // 73 (BN=64 tiles)
    const int NB_POL = GY_POL * 4;                // 292
    const int RPX    = (N / 128) / 8;             // 22 row-blocks per XCD

    char* ws = (char*)d_ws;
    size_t off = 0;
    auto alloc = [&](size_t nbytes) {
        void* pp = ws + off;
        off = (off + nbytes + 255) & ~(size_t)255;
        return pp;
    };
    unsigned short* hh = (unsigned short*)alloc((size_t)N * CN * 2);
    unsigned short* xlr = (unsigned short*)alloc((size_t)N * 512 * 2);   // bf16
    float* gtmp   = (float*)alloc((size_t)N * GATE_DIM * 4);
    unsigned short* WcatH = (unsigned short*)alloc((size_t)4 * 8 * NB_CAT * 512 * 2);
    unsigned short* gW1H  = (unsigned short*)alloc((size_t)8 * NB_G1 * 512 * 2);
    unsigned short* pW2H  = (unsigned short*)alloc((size_t)8 * NB_POL * 512 * 2);
    unsigned short* pW2L  = (unsigned short*)alloc((size_t)8 * NB_POL * 512 * 2);
    float* gate   = (float*)alloc((size_t)N * 4);
    float* emb    = (float*)alloc((size_t)G * CN * 4);
    unsigned short* t1h = (unsigned short*)alloc((size_t)G * CN * 2);
    unsigned short* t1l = (unsigned short*)alloc((size_t)G * CN * 2);
    int*   rowptr = (int*)alloc((size_t)(N + 1) * 4);
    int*   cnt    = (int*)alloc((size_t)N * 4);
    int*   cursor = (int*)alloc((size_t)N * 4);
    int*   btot   = (int*)alloc((size_t)64 * 4);
    int*   csrcB  = (int*)alloc((size_t)E * 4);

    const int* e_src = ei;
    const int* e_dst = ei + E;

    hipMemsetAsync(cnt, 0, (size_t)N * 4, stream);
    hipMemsetAsync(cursor, 0, (size_t)N * 4, stream);
    count_kernel<<<(E + 255) / 256, 256, 0, stream>>>(e_dst, cnt, E);
    scan1_kernel<<<NB_SC, 1024, 0, stream>>>(cnt, rowptr, btot, N);
    scan3_kernel<<<(N + 1024) / 1024, 1024, 0, stream>>>(rowptr, btot, N, NB_SC);
    fill_kernel<<<(E + 255) / 256, 256, 0, stream>>>(e_src, e_dst, rowptr, cursor, csrcB, E);

    embed_kernel<<<N / 16, 256, 0, stream>>>(x, W_emb, b_emb, pos_emb, hh);

    {
        int totc = 8 * NB_CAT * 512;
        dim3 gw((totc + 255) / 256, 4);
        wconv_cat_h_kernel<<<gw, 256, 0, stream>>>(gat_Wsrc, gat_Wdst, WcatH, NB_CAT, totc);
        int totg = 8 * NB_G1 * 512;
        wconv_h_kernel<<<(totg + 255) / 256, 256, 0, stream>>>(gW1, gW1H, GATE_DIM, NB_G1, totg);
        int totp = 8 * NB_POL * 512;
        wconv_kernel<<<(totp + 255) / 256, 256, 0, stream>>>(pW2, pW2H, pW2L, ACT_DIM, NB_POL, totp);
    }

    for (int l = 0; l < 4; ++l) {
        size_t wo = (size_t)l * 8 * NB_CAT * 512;
        // XCD-aligned 1D grid: 176 row-blocks x 4 col-blocks = 704 blocks
        mgemm<false, 1, true, 8, true><<<(N / 128) * 4, 256, 0, stream>>>(
            hh, nullptr, WcatH + wo, nullptr, nullptr, xlr, N, 512, NB_CAT, CN, RPX);
        gat_agg<<<N / 2, 64, 0, stream>>>(xlr, rowptr, csrcB, gat_att + l * CN,
                                          gat_bias + l * CN, ln_g + l * CN, ln_b + l * CN,
                                          hh);
    }

    // gate MLP (XCD-aligned too: 176 blocks, gy=1)
    {
        mgemm<true, 1, false, 8, true><<<N / 128, 256, 0, stream>>>(
            hh, nullptr, gW1H, nullptr, gb1, gtmp, N, GATE_DIM, NB_G1, CN, RPX);
        gate2_kernel<<<(N + 3) / 4, 256, 0, stream>>>(gtmp, gW2, gb2, gate, N);
    }
    pool_kernel<<<G, 256, 0, stream>>>(gate, hh, emb);

    float* policy = (float*)d_out;
    float* value  = (float*)d_out + (size_t)G * ACT_DIM;
    head_kernel<<<G, 256, 0, stream>>>(emb, pW1, pb1, p_ln_g, p_ln_b,
                                       vW1, vb1, vW2, vb2, t1h, t1l, value);
    dim3 g2(G / 128, GY_POL);
    mgemm<true, 3, false, 4, false><<<g2, 256, 0, stream>>>(t1h, t1l, pW2H, pW2L, pb2,
                                                            policy, G, ACT_DIM, NB_POL, CN, 0);
}

// Round 20
// 271.466 us; speedup vs baseline: 1.0771x; 1.0241x over previous
//
#include <hip/hip_runtime.h>
#include <math.h>

constexpr int CN = 256;        // channels
constexpr int NHEAD = 8;       // attention heads
constexpr int KPG = 88;        // nodes per graph
constexpr int NIDF = 16;       // input node features
constexpr int GATE_DIM = 128;
constexpr int ACT_DIM = 4644;
constexpr float LOG2E = 1.4426950408889634f;

typedef __attribute__((ext_vector_type(8))) short bf16x8;
typedef __attribute__((ext_vector_type(4))) float f32x4;

__device__ __forceinline__ unsigned short f2bf(float f) {
    unsigned int u = __float_as_uint(f);
    unsigned int r = (u + 0x7fffu + ((u >> 16) & 1u)) >> 16;
    return (unsigned short)r;
}
__device__ __forceinline__ float bf2f(unsigned short h) {
    return __uint_as_float(((unsigned int)h) << 16);
}

__device__ __forceinline__ void glds16(const void* g, void* l) {
    __builtin_amdgcn_global_load_lds(
        (const __attribute__((address_space(1))) unsigned int*)g,
        (__attribute__((address_space(3))) unsigned int*)l, 16, 0, 0);
}

// raw v_exp_f32: w = 2^x  (inputs pre-scaled by log2e; clamped <= 80, -inf -> 0)
__device__ __forceinline__ float fexp2(float x) {
    float r;
    asm("v_exp_f32 %0, %1" : "=v"(r) : "v"(x));
    return r;
}

// 8-lane group sum via DPP (VALU-speed, no LDS pipe)
__device__ __forceinline__ float grp8_sum(float p) {
    int t;
    t = __builtin_amdgcn_mov_dpp(__float_as_int(p), 0xB1, 0xF, 0xF, true);
    p += __int_as_float(t);
    t = __builtin_amdgcn_mov_dpp(__float_as_int(p), 0x4E, 0xF, 0xF, true);
    p += __int_as_float(t);
    t = __builtin_amdgcn_mov_dpp(__float_as_int(p), 0x141, 0xF, 0xF, true);
    p += __int_as_float(t);
    return p;
}

// ---------------------------------------------------------------------------
// CSR build: count -> scan1 -> scan3 (also seeds cursor) -> fill
// ---------------------------------------------------------------------------
__global__ void count_kernel(const int* __restrict__ dst, int* __restrict__ cnt, int E) {
    int e = blockIdx.x * 256 + threadIdx.x;
    if (e < E) atomicAdd(&cnt[dst[e]], 1);
}

__global__ __launch_bounds__(1024) void scan1_kernel(const int* __restrict__ cnt,
                                                     int* __restrict__ rowptr,
                                                     int* __restrict__ btot, int n) {
    __shared__ int buf[1024];
    int tid = threadIdx.x;
    int i = blockIdx.x * 1024 + tid;
    int v = (i < n) ? cnt[i] : 0;
    buf[tid] = v;
    __syncthreads();
    for (int off = 1; off < 1024; off <<= 1) {
        int t = (tid >= off) ? buf[tid - off] : 0;
        __syncthreads();
        buf[tid] += t;
        __syncthreads();
    }
    if (i < n) rowptr[i] = buf[tid] - v;
    if (tid == 1023) btot[blockIdx.x] = buf[1023];
}

// adds prefix of btot inline; also seeds cursor with the final rowptr value
__global__ __launch_bounds__(1024) void scan3_kernel(int* __restrict__ rowptr,
                                                     int* __restrict__ cursor,
                                                     const int* __restrict__ btot,
                                                     int n, int nb) {
    int i = blockIdx.x * 1024 + threadIdx.x;
    int b = i >> 10;
    if (i < n) {
        int pre = 0;
        for (int k = 0; k < b; ++k) pre += btot[k];
        int v = rowptr[i] + pre;
        rowptr[i] = v;
        cursor[i] = v;
    } else if (i == n) {
        int pre = 0;
        for (int k = 0; k < nb; ++k) pre += btot[k];
        rowptr[n] = pre;
    }
}

__global__ void fill_kernel(const int* __restrict__ src, const int* __restrict__ dst,
                            int* __restrict__ cursor, int* __restrict__ csrcB, int E) {
    int e = blockIdx.x * 256 + threadIdx.x;
    if (e < E) {
        int p = atomicAdd(&cursor[dst[e]], 1);
        csrcB[p] = src[e] * 1024;   // byte offset into bf16 xlr (512 bf16/row)
    }
}

// ---------------------------------------------------------------------------
// Embedding: hh = bf16(relu(x @ W_emb + b_emb) + pos_emb[n % 88])
// ---------------------------------------------------------------------------
__global__ __launch_bounds__(256) void embed_kernel(const float* __restrict__ x,
                                                    const float* __restrict__ Wemb,
                                                    const float* __restrict__ bemb,
                                                    const float* __restrict__ pos,
                                                    unsigned short* __restrict__ hh) {
    __shared__ float Wl[NIDF][CN];
    int tid = threadIdx.x;
    for (int i = tid; i < NIDF * CN; i += 256) Wl[i >> 8][i & 255] = Wemb[i];
    __syncthreads();
    float bias = bemb[tid];
    int node0 = blockIdx.x * 16;
    for (int q = 0; q < 16; ++q) {
        int n = node0 + q;
        float acc = bias;
        #pragma unroll
        for (int k = 0; k < NIDF; ++k) acc += x[n * NIDF + k] * Wl[k][tid];
        float val = fmaxf(acc, 0.f) + pos[(n % KPG) * CN + tid];
        hh[(size_t)n * CN + tid] = f2bf(val);
    }
}

// ---------------------------------------------------------------------------
// Weight relayout kernels. *_h variants emit bf16 hi only (for PROD=1 GEMMs).
// ---------------------------------------------------------------------------
__global__ void wconv_cat_h_kernel(const float* __restrict__ Ws, const float* __restrict__ Wd,
                                   unsigned short* __restrict__ Bh, int NB, int tot) {
    int o = blockIdx.x * 256 + threadIdx.x;
    if (o >= tot) return;
    int l4 = blockIdx.y;
    const float* ws = Ws + (size_t)l4 * 256 * 256;
    const float* wd = Wd + (size_t)l4 * 256 * 256;
    int idx = o & 511;
    int nb = (o >> 9) % NB;
    int kb = o / (512 * NB);
    int l = idx >> 3, j = idx & 7;
    int k = kb * 32 + (l >> 4) * 8 + j;
    int c = nb * 16 + (l & 15);
    float v = (c < 256) ? ws[(size_t)k * 256 + c] : wd[(size_t)k * 256 + (c - 256)];
    Bh[(size_t)l4 * tot + o] = f2bf(v);
}

__global__ void wconv_h_kernel(const float* __restrict__ W, unsigned short* __restrict__ Bh,
                               int Nn, int NB, int tot) {
    int o = blockIdx.x * 256 + threadIdx.x;
    if (o >= tot) return;
    int idx = o & 511;
    int nb = (o >> 9) % NB;
    int kb = o / (512 * NB);
    int l = idx >> 3, j = idx & 7;
    int k = kb * 32 + (l >> 4) * 8 + j;
    int c = nb * 16 + (l & 15);
    float v = (c < Nn) ? W[(size_t)k * Nn + c] : 0.f;
    Bh[o] = f2bf(v);
}

__global__ void wconv_kernel(const float* __restrict__ W, unsigned short* __restrict__ Bh,
                             unsigned short* __restrict__ Bl, int Nn, int NB, int tot) {
    int o = blockIdx.x * 256 + threadIdx.x;
    if (o >= tot) return;
    int idx = o & 511;
    int nb = (o >> 9) % NB;
    int kb = o / (512 * NB);
    int l = idx >> 3, j = idx & 7;
    int k = kb * 32 + (l >> 4) * 8 + j;
    int c = nb * 16 + (l & 15);
    float v = (c < Nn) ? W[(size_t)k * Nn + c] : 0.f;
    unsigned short hh = f2bf(v);
    Bh[o] = hh;
    Bl[o] = f2bf(v - bf2f(hh));
}

// ---------------------------------------------------------------------------
// MFMA GEMM, bf16 split: C = A @ B (+bias).
// PROD=1: AhBh only. PROD=2: +AhBl. PROD=3: +AlBh.
// OBF16 : emit C as bf16.  NBT: B-tile width in 16-col blocks.
// XSWZ  : 1D grid, XCD-aligned decomposition.
// GATE  : fused gate epilogue — Cv = gate[N] = relu(C+bias).gw2 + gb2v[0]
// ---------------------------------------------------------------------------
template <bool BIAS, int PROD, bool OBF16, int NBT, bool XSWZ, bool GATE>
__global__ __launch_bounds__(256) void mgemm(const unsigned short* __restrict__ Ah,
                                             const unsigned short* __restrict__ Al,
                                             const unsigned short* __restrict__ Bh,
                                             const unsigned short* __restrict__ Bl,
                                             const float* __restrict__ bias,
                                             void* __restrict__ Cv,
                                             int M, int Nlog, int NB, int K, int RPX,
                                             const float* __restrict__ gw2,
                                             const float* __restrict__ gb2v) {
    constexpr int NF = NBT / 2;           // per-wave N fragments
    __shared__ unsigned short AhL[8 * 64 * 8];
    __shared__ unsigned short AlL[(PROD >= 3) ? 8 * 64 * 8 : 16];
    __shared__ unsigned short BhL[NBT * 512];
    __shared__ unsigned short BlL[(PROD >= 2) ? NBT * 512 : 16];
    __shared__ float gpart[GATE ? 2 : 1][GATE ? 128 : 1];
    int tid = threadIdx.x;
    int wid = tid >> 6, lane = tid & 63;
    int bx, cb;
    if constexpr (XSWZ) {
        int b = blockIdx.x;
        int xcd = b & 7;
        int i = b >> 3;
        bx = xcd * RPX + i % RPX;
        cb = i / RPX;
    } else {
        bx = blockIdx.x;
        cb = blockIdx.y;
    }
    int row0 = bx * 128;
    int wr = wid >> 1, wc = wid & 1;

    int rr = lane & 15, kq = lane >> 4;

    f32x4 acc[4][NF] = {};

    for (int k0 = 0; k0 < K; k0 += 32) {
        int kb = k0 >> 5;
        {
            int mb0 = wid * 2;
            const unsigned short* s0 = Ah + (size_t)(row0 + mb0 * 16 + rr) * K + k0 + kq * 8;
            const unsigned short* s1 = Ah + (size_t)(row0 + mb0 * 16 + 16 + rr) * K + k0 + kq * 8;
            glds16(s0, &AhL[mb0 * 512]);
            glds16(s1, &AhL[mb0 * 512 + 512]);
            if constexpr (PROD >= 3) {
                const unsigned short* t0 = Al + (size_t)(row0 + mb0 * 16 + rr) * K + k0 + kq * 8;
                const unsigned short* t1 = Al + (size_t)(row0 + mb0 * 16 + 16 + rr) * K + k0 + kq * 8;
                glds16(t0, &AlL[mb0 * 512]);
                glds16(t1, &AlL[mb0 * 512 + 512]);
            }
        }
        {
            size_t base = ((size_t)kb * NB + (size_t)cb * NBT) * 512;
            for (int ch = wid; ch < NBT; ch += 4) {
                glds16(Bh + base + ch * 512 + lane * 8, &BhL[ch * 512]);
                if constexpr (PROD >= 2)
                    glds16(Bl + base + ch * 512 + lane * 8, &BlL[ch * 512]);
            }
        }
        __syncthreads();
        bf16x8 a_h[4], a_l[4], b_h[NF], b_l[NF];
        #pragma unroll
        for (int mf = 0; mf < 4; ++mf) {
            int off = ((wr * 4 + mf) * 64 + lane) * 8;
            a_h[mf] = *reinterpret_cast<const bf16x8*>(&AhL[off]);
            if constexpr (PROD >= 3)
                a_l[mf] = *reinterpret_cast<const bf16x8*>(&AlL[off]);
        }
        #pragma unroll
        for (int nf = 0; nf < NF; ++nf) {
            int off = ((wc * NF + nf) * 64 + lane) * 8;
            b_h[nf] = *reinterpret_cast<const bf16x8*>(&BhL[off]);
            if constexpr (PROD >= 2)
                b_l[nf] = *reinterpret_cast<const bf16x8*>(&BlL[off]);
        }
        #pragma unroll
        for (int mf = 0; mf < 4; ++mf)
            #pragma unroll
            for (int nf = 0; nf < NF; ++nf) {
                acc[mf][nf] = __builtin_amdgcn_mfma_f32_16x16x32_bf16(a_h[mf], b_h[nf], acc[mf][nf], 0, 0, 0);
                if constexpr (PROD >= 2)
                    acc[mf][nf] = __builtin_amdgcn_mfma_f32_16x16x32_bf16(a_h[mf], b_l[nf], acc[mf][nf], 0, 0, 0);
                if constexpr (PROD >= 3)
                    acc[mf][nf] = __builtin_amdgcn_mfma_f32_16x16x32_bf16(a_l[mf], b_h[nf], acc[mf][nf], 0, 0, 0);
            }
        __syncthreads();
    }
    if constexpr (GATE) {
        // gate fusion: Nlog == 128, cb == 0. Per-thread cols: wc*64+nf*16+(lane&15)
        float part[4][4];
        #pragma unroll
        for (int mf = 0; mf < 4; ++mf) {
            #pragma unroll
            for (int rg = 0; rg < 4; ++rg) {
                float s = 0.f;
                #pragma unroll
                for (int nf = 0; nf < NF; ++nf) {
                    int col = wc * (NF * 16) + nf * 16 + (lane & 15);
                    float r = fmaxf(acc[mf][nf][rg] + bias[col], 0.f);
                    s += r * gw2[col];
                }
                // reduce over the 16 lanes of (lane&15)
                s += __shfl_xor(s, 1);
                s += __shfl_xor(s, 2);
                s += __shfl_xor(s, 4);
                s += __shfl_xor(s, 8);
                part[mf][rg] = s;
            }
        }
        if ((lane & 15) == 0) {
            #pragma unroll
            for (int mf = 0; mf < 4; ++mf)
                #pragma unroll
                for (int rg = 0; rg < 4; ++rg)
                    gpart[wc][wr * 64 + mf * 16 + (lane >> 4) * 4 + rg] = part[mf][rg];
        }
        __syncthreads();
        if (tid < 128)
            ((float*)Cv)[row0 + tid] = gpart[0][tid] + gpart[1][tid] + gb2v[0];
    } else {
        #pragma unroll
        for (int mf = 0; mf < 4; ++mf) {
            #pragma unroll
            for (int nf = 0; nf < NF; ++nf) {
                int col = cb * (NBT * 16) + wc * (NF * 16) + nf * 16 + (lane & 15);
                if (col < Nlog) {
                    float bv = BIAS ? bias[col] : 0.f;
                    #pragma unroll
                    for (int rg = 0; rg < 4; ++rg) {
                        int row = row0 + wr * 64 + mf * 16 + (lane >> 4) * 4 + rg;
                        float r = acc[mf][nf][rg] + bv;
                        if constexpr (OBF16)
                            ((unsigned short*)Cv)[(size_t)row * Nlog + col] = f2bf(r);
                        else
                            ((float*)Cv)[(size_t)row * Nlog + col] = r;
                    }
                }
            }
        }
    }
}

// ---------------------------------------------------------------------------
// GAT aggregate v15: residual + output both in bf16 hh (no fp32 h buffer).
// One wave per block, two consecutive nodes per wave, compute/refill
// alternation, bf16 xlr gather, scalarized CSR walk, base-2 no-max softmax,
// DPP reduce, XCD swizzle.
// ---------------------------------------------------------------------------
__global__ __launch_bounds__(64) void gat_agg(const unsigned short* __restrict__ xlr,
                                              const int* __restrict__ rowptr,
                                              const int* __restrict__ csrcB,
                                              const float* __restrict__ att,
                                              const float* __restrict__ bias,
                                              const float* __restrict__ lng,
                                              const float* __restrict__ lnb,
                                              unsigned short* __restrict__ hh) {
    int cpx = gridDim.x >> 3;
    int swz = (blockIdx.x & 7) * cpx + (blockIdx.x >> 3);
    int lane = threadIdx.x;
    int na = __builtin_amdgcn_readfirstlane(swz * 2);
    int nb_ = na + 1;
    int voff = lane * 8;                      // byte offset (4 bf16/lane)

    ushort4 ua = *reinterpret_cast<const ushort4*>(xlr + (size_t)na * 512 + 256 + lane * 4);
    ushort4 ub = *reinterpret_cast<const ushort4*>(xlr + (size_t)nb_ * 512 + 256 + lane * 4);
    float xa0 = bf2f(ua.x), xa1 = bf2f(ua.y), xa2 = bf2f(ua.z), xa3 = bf2f(ua.w);
    float xb0 = bf2f(ub.x), xb1 = bf2f(ub.y), xb2 = bf2f(ub.z), xb3 = bf2f(ub.w);
    float4 at4 = *reinterpret_cast<const float4*>(att + lane * 4);
    at4.x *= LOG2E; at4.y *= LOG2E; at4.z *= LOG2E; at4.w *= LOG2E;

    int e0a = __builtin_amdgcn_readfirstlane(rowptr[na]);
    int e1a = __builtin_amdgcn_readfirstlane(rowptr[na + 1]);
    int e1b = __builtin_amdgcn_readfirstlane(rowptr[nb_ + 1]);
    int e0b = e1a;   // consecutive nodes, contiguous CSR

    float sA = 0.f, aA0 = 0.f, aA1 = 0.f, aA2 = 0.f, aA3 = 0.f;
    float sB = 0.f, aB0 = 0.f, aB1 = 0.f, aB2 = 0.f, aB3 = 0.f;
    const char* xB = (const char*)xlr;

    auto ld4 = [&](ushort4* X, int eb, int last) {
        if (eb + 3 <= last) {
            #pragma unroll
            for (int j = 0; j < 4; ++j) {
                int f = csrcB[eb + j];
                X[j] = *reinterpret_cast<const ushort4*>(xB + (unsigned)f + voff);
            }
        } else {
            #pragma unroll
            for (int j = 0; j < 4; ++j) {
                int f = csrcB[min(eb + j, last)];
                X[j] = *reinterpret_cast<const ushort4*>(xB + (unsigned)f + voff);
            }
        }
    };
    auto group4 = [&](const ushort4* X, int eb, int e1,
                      float xr0, float xr1, float xr2, float xr3,
                      float& s_r, float& a0, float& a1, float& a2, float& a3) {
        float xf[4][4];
        #pragma unroll
        for (int j = 0; j < 4; ++j) {
            xf[j][0] = bf2f(X[j].x);
            xf[j][1] = bf2f(X[j].y);
            xf[j][2] = bf2f(X[j].z);
            xf[j][3] = bf2f(X[j].w);
        }
        float p[4];
        #pragma unroll
        for (int j = 0; j < 4; ++j) {
            float z, pp = 0.f;
            z = xf[j][0] + xr0; z = fmaxf(z, 0.2f * z); pp += z * at4.x;
            z = xf[j][1] + xr1; z = fmaxf(z, 0.2f * z); pp += z * at4.y;
            z = xf[j][2] + xr2; z = fmaxf(z, 0.2f * z); pp += z * at4.z;
            z = xf[j][3] + xr3; z = fmaxf(z, 0.2f * z); pp += z * at4.w;
            p[j] = grp8_sum(pp);
        }
        float w[4];
        if (eb + 3 < e1) {
            #pragma unroll
            for (int j = 0; j < 4; ++j) w[j] = fexp2(fminf(p[j], 80.f));
        } else {
            #pragma unroll
            for (int j = 0; j < 4; ++j) {
                float pc = (eb + j < e1) ? fminf(p[j], 80.f) : -INFINITY;
                w[j] = fexp2(pc);
            }
        }
        s_r += (w[0] + w[1]) + (w[2] + w[3]);
        #pragma unroll
        for (int j = 0; j < 4; ++j) {
            a0 += w[j] * xf[j][0];
            a1 += w[j] * xf[j][1];
            a2 += w[j] * xf[j][2];
            a3 += w[j] * xf[j][3];
        }
    };

    ushort4 A[4], B[4], T[4];
    int eA = e0a, eB = e0b;
    ld4(A, eA, e1a - 1);
    ld4(B, eB, e1b - 1);
    while (eA < e1a || eB < e1b) {
        if (eA < e1a) {
            #pragma unroll
            for (int j = 0; j < 4; ++j) T[j] = A[j];
            if (eA + 4 < e1a) ld4(A, eA + 4, e1a - 1);
            group4(T, eA, e1a, xa0, xa1, xa2, xa3, sA, aA0, aA1, aA2, aA3);
            eA += 4;
        }
        if (eB < e1b) {
            #pragma unroll
            for (int j = 0; j < 4; ++j) T[j] = B[j];
            if (eB + 4 < e1b) ld4(B, eB + 4, e1b - 1);
            group4(T, eB, e1b, xb0, xb1, xb2, xb3, sB, aB0, aB1, aB2, aB3);
            eB += 4;
        }
    }

    auto finish = [&](int n, float s_r, float a0, float a1, float a2, float a3) {
        float inv = 1.f / s_r;
        ushort4 hr = *reinterpret_cast<const ushort4*>(hh + (size_t)n * CN + lane * 4);
        float4 bi4 = *reinterpret_cast<const float4*>(bias + lane * 4);
        float v0 = bf2f(hr.x) + fmaxf(a0 * inv + bi4.x, 0.f);
        float v1 = bf2f(hr.y) + fmaxf(a1 * inv + bi4.y, 0.f);
        float v2 = bf2f(hr.z) + fmaxf(a2 * inv + bi4.z, 0.f);
        float v3 = bf2f(hr.w) + fmaxf(a3 * inv + bi4.w, 0.f);
        float sum = v0 + v1 + v2 + v3;
        float sq = v0 * v0 + v1 * v1 + v2 * v2 + v3 * v3;
        #pragma unroll
        for (int o = 32; o; o >>= 1) { sum += __shfl_xor(sum, o); sq += __shfl_xor(sq, o); }
        float mu = sum / CN;
        float var = sq / CN - mu * mu;
        float ninv = rsqrtf(var + 1e-5f);
        float4 lg4 = *reinterpret_cast<const float4*>(lng + lane * 4);
        float4 lb4 = *reinterpret_cast<const float4*>(lnb + lane * 4);
        float o0 = (v0 - mu) * ninv * lg4.x + lb4.x;
        float o1 = (v1 - mu) * ninv * lg4.y + lb4.y;
        float o2 = (v2 - mu) * ninv * lg4.z + lb4.z;
        float o3 = (v3 - mu) * ninv * lg4.w + lb4.w;
        ushort4 uh;
        uh.x = f2bf(o0); uh.y = f2bf(o1); uh.z = f2bf(o2); uh.w = f2bf(o3);
        *reinterpret_cast<ushort4*>(hh + (size_t)n * CN + lane * 4) = uh;
    };
    finish(na, sA, aA0, aA1, aA2, aA3);
    finish(nb_, sB, aB0, aB1, aB2, aB3);
}

// ---------------------------------------------------------------------------
// Pool: segment softmax over contiguous 88-node graphs + weighted sum -> emb
// (reads bf16 hh)
// ---------------------------------------------------------------------------
__global__ __launch_bounds__(256) void pool_kernel(const float* __restrict__ gate,
                                                   const unsigned short* __restrict__ hh,
                                                   float* __restrict__ emb) {
    __shared__ float a[KPG];
    __shared__ float wm[4];
    int g = blockIdx.x, tid = threadIdx.x;
    int wid = tid >> 6, lane = tid & 63;
    float gv = (tid < KPG) ? gate[g * KPG + tid] : -INFINITY;
    float m = gv;
    #pragma unroll
    for (int o = 32; o; o >>= 1) m = fmaxf(m, __shfl_xor(m, o));
    if (lane == 0) wm[wid] = m;
    __syncthreads();
    m = fmaxf(fmaxf(wm[0], wm[1]), fmaxf(wm[2], wm[3]));
    __syncthreads();
    float av = (tid < KPG) ? expf(gv - m) : 0.f;
    if (tid < KPG) a[tid] = av;
    float s = av;
    #pragma unroll
    for (int o = 32; o; o >>= 1) s += __shfl_xor(s, o);
    if (lane == 0) wm[wid] = s;
    __syncthreads();
    s = wm[0] + wm[1] + wm[2] + wm[3];
    float inv = 1.f / s;
    float acc = 0.f;
    const unsigned short* hg = hh + (size_t)g * KPG * CN;
    for (int i = 0; i < KPG; ++i) acc += a[i] * bf2f(hg[i * CN + tid]);
    emb[(size_t)g * CN + tid] = acc * inv;
}

// ---------------------------------------------------------------------------
// Heads: t1 = relu(LN(emb@pW1+pb1)) (bf16 hi/lo out); value head full
// ---------------------------------------------------------------------------
__global__ __launch_bounds__(256) void head_kernel(const float* __restrict__ emb,
    const float* __restrict__ pW1, const float* __restrict__ pb1,
    const float* __restrict__ plng, const float* __restrict__ plnb,
    const float* __restrict__ vW1, const float* __restrict__ vb1,
    const float* __restrict__ vW2, const float* __restrict__ vb2,
    unsigned short* __restrict__ t1h, unsigned short* __restrict__ t1l,
    float* __restrict__ value_out) {
    __shared__ float e_l[CN];
    __shared__ float rsum[4], rsq[4];
    int g = blockIdx.x, tid = threadIdx.x;
    int wid = tid >> 6, lane = tid & 63;
    e_l[tid] = emb[(size_t)g * CN + tid];
    __syncthreads();
    float p = pb1[tid], v = vb1[tid];
    for (int k = 0; k < CN; ++k) {
        float e = e_l[k];
        p += e * pW1[k * CN + tid];
        v += e * vW1[k * CN + tid];
    }
    float sum = p, sq = p * p;
    #pragma unroll
    for (int o = 32; o; o >>= 1) { sum += __shfl_xor(sum, o); sq += __shfl_xor(sq, o); }
    if (lane == 0) { rsum[wid] = sum; rsq[wid] = sq; }
    __syncthreads();
    sum = rsum[0] + rsum[1] + rsum[2] + rsum[3];
    sq  = rsq[0] + rsq[1] + rsq[2] + rsq[3];
    float mu = sum / CN;
    float var = sq / CN - mu * mu;
    float inv = rsqrtf(var + 1e-5f);
    float t1v = fmaxf((p - mu) * inv * plng[tid] + plnb[tid], 0.f);
    unsigned short th = f2bf(t1v);
    t1h[(size_t)g * CN + tid] = th;
    t1l[(size_t)g * CN + tid] = f2bf(t1v - bf2f(th));
    float contrib = fmaxf(v, 0.f) * vW2[tid];
    __syncthreads();
    #pragma unroll
    for (int o = 32; o; o >>= 1) contrib += __shfl_xor(contrib, o);
    if (lane == 0) rsum[wid] = contrib;
    __syncthreads();
    if (tid == 0)
        value_out[g] = tanhf(rsum[0] + rsum[1] + rsum[2] + rsum[3] + vb2[0]);
}

// ---------------------------------------------------------------------------
extern "C" void kernel_launch(void* const* d_in, const int* in_sizes, int n_in,
                              void* d_out, int out_size, void* d_ws, size_t ws_size,
                              hipStream_t stream) {
    const float* x        = (const float*)d_in[0];
    const int*   ei       = (const int*)d_in[1];
    const float* W_emb    = (const float*)d_in[4];
    const float* b_emb    = (const float*)d_in[5];
    const float* pos_emb  = (const float*)d_in[6];
    const float* gat_Wsrc = (const float*)d_in[7];
    const float* gat_Wdst = (const float*)d_in[8];
    const float* gat_att  = (const float*)d_in[9];
    const float* gat_bias = (const float*)d_in[10];
    const float* ln_g     = (const float*)d_in[11];
    const float* ln_b     = (const float*)d_in[12];
    const float* gW1      = (const float*)d_in[13];
    const float* gb1      = (const float*)d_in[14];
    const float* gW2      = (const float*)d_in[15];
    const float* gb2      = (const float*)d_in[16];
    const float* pW1      = (const float*)d_in[17];
    const float* pb1      = (const float*)d_in[18];
    const float* p_ln_g   = (const float*)d_in[19];
    const float* p_ln_b   = (const float*)d_in[20];
    const float* pW2      = (const float*)d_in[21];
    const float* pb2      = (const float*)d_in[22];
    const float* vW1      = (const float*)d_in[23];
    const float* vb1      = (const float*)d_in[24];
    const float* vW2      = (const float*)d_in[25];
    const float* vb2      = (const float*)d_in[26];

    const int N = in_sizes[2];      // 22528
    const int E = in_sizes[1] / 2;  // 405504
    const int G = N / KPG;          // 256
    const int NB_SC = (N + 1023) / 1024;

    const int NB_CAT = 32;                        // 512/16
    const int NB_G1  = 8;                         // 128/16
    const int GY_POL = (ACT_DIM + 63) / 64;       // 73 (BN=64 tiles)
    const int NB_POL = GY_POL * 4;                // 292
    const int RPX    = (N / 128) / 8;             // 22 row-blocks per XCD

    char* ws = (char*)d_ws;
    size_t off = 0;
    auto alloc = [&](size_t nbytes) {
        void* pp = ws + off;
        off = (off + nbytes + 255) & ~(size_t)255;
        return pp;
    };
    unsigned short* hh = (unsigned short*)alloc((size_t)N * CN * 2);
    unsigned short* xlr = (unsigned short*)alloc((size_t)N * 512 * 2);   // bf16
    unsigned short* WcatH = (unsigned short*)alloc((size_t)4 * 8 * NB_CAT * 512 * 2);
    unsigned short* gW1H  = (unsigned short*)alloc((size_t)8 * NB_G1 * 512 * 2);
    unsigned short* pW2H  = (unsigned short*)alloc((size_t)8 * NB_POL * 512 * 2);
    unsigned short* pW2L  = (unsigned short*)alloc((size_t)8 * NB_POL * 512 * 2);
    float* gate   = (float*)alloc((size_t)N * 4);
    float* emb    = (float*)alloc((size_t)G * CN * 4);
    unsigned short* t1h = (unsigned short*)alloc((size_t)G * CN * 2);
    unsigned short* t1l = (unsigned short*)alloc((size_t)G * CN * 2);
    int*   rowptr = (int*)alloc((size_t)(N + 1) * 4);
    int*   cnt    = (int*)alloc((size_t)N * 4);
    int*   cursor = (int*)alloc((size_t)N * 4);
    int*   btot   = (int*)alloc((size_t)64 * 4);
    int*   csrcB  = (int*)alloc((size_t)E * 4);

    const int* e_src = ei;
    const int* e_dst = ei + E;

    hipMemsetAsync(cnt, 0, (size_t)N * 4, stream);
    count_kernel<<<(E + 255) / 256, 256, 0, stream>>>(e_dst, cnt, E);
    scan1_kernel<<<NB_SC, 1024, 0, stream>>>(cnt, rowptr, btot, N);
    scan3_kernel<<<(N + 1024) / 1024, 1024, 0, stream>>>(rowptr, cursor, btot, N, NB_SC);
    fill_kernel<<<(E + 255) / 256, 256, 0, stream>>>(e_src, e_dst, cursor, csrcB, E);

    embed_kernel<<<N / 16, 256, 0, stream>>>(x, W_emb, b_emb, pos_emb, hh);

    {
        int totc = 8 * NB_CAT * 512;
        dim3 gw((totc + 255) / 256, 4);
        wconv_cat_h_kernel<<<gw, 256, 0, stream>>>(gat_Wsrc, gat_Wdst, WcatH, NB_CAT, totc);
        int totg = 8 * NB_G1 * 512;
        wconv_h_kernel<<<(totg + 255) / 256, 256, 0, stream>>>(gW1, gW1H, GATE_DIM, NB_G1, totg);
        int totp = 8 * NB_POL * 512;
        wconv_kernel<<<(totp + 255) / 256, 256, 0, stream>>>(pW2, pW2H, pW2L, ACT_DIM, NB_POL, totp);
    }

    for (int l = 0; l < 4; ++l) {
        size_t wo = (size_t)l * 8 * NB_CAT * 512;
        // XCD-aligned 1D grid: 176 row-blocks x 4 col-blocks = 704 blocks
        mgemm<false, 1, true, 8, true, false><<<(N / 128) * 4, 256, 0, stream>>>(
            hh, nullptr, WcatH + wo, nullptr, nullptr, xlr, N, 512, NB_CAT, CN, RPX,
            nullptr, nullptr);
        gat_agg<<<N / 2, 64, 0, stream>>>(xlr, rowptr, csrcB, gat_att + l * CN,
                                          gat_bias + l * CN, ln_g + l * CN, ln_b + l * CN,
                                          hh);
    }

    // gate MLP fully fused into one GEMM (gate epilogue)
    mgemm<true, 1, false, 8, true, true><<<N / 128, 256, 0, stream>>>(
        hh, nullptr, gW1H, nullptr, gb1, gate, N, GATE_DIM, NB_G1, CN, RPX,
        gW2, gb2);
    pool_kernel<<<G, 256, 0, stream>>>(gate, hh, emb);

    float* policy = (float*)d_out;
    float* value  = (float*)d_out + (size_t)G * ACT_DIM;
    head_kernel<<<G, 256, 0, stream>>>(emb, pW1, pb1, p_ln_g, p_ln_b,
                                       vW1, vb1, vW2, vb2, t1h, t1l, value);
    dim3 g2(G / 128, GY_POL);
    mgemm<true, 3, false, 4, false, false><<<g2, 256, 0, stream>>>(
        t1h, t1l, pW2H, pW2L, pb2, policy, G, ACT_DIM, NB_POL, CN, 0,
        nullptr, nullptr);
}